// Round 1
// baseline (1911.268 us; speedup 1.0000x reference)
//
#include <hip/hip_runtime.h>
#include <cstddef>
#include <cstdint>

// Problem constants (from reference)
#define NN 100000
#define NE 1600000
// F_IN=16, HID=128, OUT=4, K=3

// ---------------------------------------------------------------------------
// Graph preprocessing
// ---------------------------------------------------------------------------

// deg[c] += ew[e]; cnt[c] += 1  over all edges
__global__ void deg_count_k(const int* __restrict__ col, const float* __restrict__ ew,
                            float* __restrict__ deg, int* __restrict__ cnt) {
    for (int e = blockIdx.x * blockDim.x + threadIdx.x; e < NE; e += gridDim.x * blockDim.x) {
        int c = col[e];
        atomicAdd(&deg[c], ew[e]);
        atomicAdd(&cnt[c], 1);
    }
}

// deg -> dis = (deg>0) ? 1/sqrt(deg) : 0   (in place)
__global__ void dis_k(float* __restrict__ deg) {
    int i = blockIdx.x * blockDim.x + threadIdx.x;
    if (i < NN) {
        float d = deg[i];
        deg[i] = (d > 0.f) ? (1.0f / sqrtf(d)) : 0.f;
    }
}

// Block-wise exclusive scan (Hillis-Steele in LDS), 256/block
__global__ void scan1_k(const int* __restrict__ cnt, int* __restrict__ exc,
                        int* __restrict__ blksum) {
    __shared__ int sm[256];
    int i = blockIdx.x * 256 + threadIdx.x;
    int v = (i < NN) ? cnt[i] : 0;
    sm[threadIdx.x] = v;
    __syncthreads();
    for (int off = 1; off < 256; off <<= 1) {
        int t = (threadIdx.x >= off) ? sm[threadIdx.x - off] : 0;
        __syncthreads();
        sm[threadIdx.x] += t;
        __syncthreads();
    }
    if (i < NN) exc[i] = sm[threadIdx.x] - v;   // exclusive within block
    if (threadIdx.x == 255) blksum[blockIdx.x] = sm[255];
}

// Exclusive scan of block sums (nb <= 512), single block of 512
__global__ void scan2_k(int* __restrict__ blksum, int nb) {
    __shared__ int sm[512];
    int t = threadIdx.x;
    int v = (t < nb) ? blksum[t] : 0;
    sm[t] = v;
    __syncthreads();
    for (int off = 1; off < 512; off <<= 1) {
        int x = (t >= off) ? sm[t - off] : 0;
        __syncthreads();
        sm[t] += x;
        __syncthreads();
    }
    if (t < nb) blksum[t] = sm[t] - v;          // exclusive
}

// rowptr[i] = exc[i] + blkoff; cursor[i] = same; rowptr[NN] = NE
__global__ void scan3_k(int* __restrict__ rowptr, int* __restrict__ cursor,
                        const int* __restrict__ blksum) {
    int i = blockIdx.x * 256 + threadIdx.x;
    if (i < NN) {
        int val = rowptr[i] + blksum[blockIdx.x];
        rowptr[i] = val;
        cursor[i] = val;
    }
    if (i == 0) rowptr[NN] = NE;
}

// Scatter edges into CSR-by-destination; store (src, norm)
__global__ void scatter_k(const int* __restrict__ row, const int* __restrict__ col,
                          const float* __restrict__ ew, const float* __restrict__ dis,
                          int* __restrict__ cursor, int* __restrict__ csrc,
                          float* __restrict__ cw) {
    for (int e = blockIdx.x * blockDim.x + threadIdx.x; e < NE; e += gridDim.x * blockDim.x) {
        int r = row[e], c = col[e];
        float w = dis[r] * ew[e] * dis[c];
        int p = atomicAdd(&cursor[c], 1);
        csrc[p] = r;
        cw[p] = w;
    }
}

// ---------------------------------------------------------------------------
// Propagation: hout[v][:] = sum_{e: col=v} norm_e * hin[src_e][:]
// ---------------------------------------------------------------------------

// 16-wide features: thread = (v, f), 16 threads per node
__global__ void prop16_k(const float* __restrict__ hin, float* __restrict__ hout,
                         const int* __restrict__ rowptr, const int* __restrict__ csrc,
                         const float* __restrict__ cw) {
    int t = blockIdx.x * 256 + threadIdx.x;   // grid sized exactly NN*16
    int v = t >> 4, f = t & 15;
    int s = rowptr[v], e = rowptr[v + 1];
    float acc = 0.f;
    for (int i = s; i < e; ++i)
        acc += cw[i] * hin[(size_t)csrc[i] * 16 + f];
    hout[(size_t)v * 16 + f] = acc;
}

// 128-wide features: thread = (v, j); v is wave-uniform (128 thr/node, 256 blk)
__global__ void prop128_k(const float* __restrict__ hin, float* __restrict__ hout,
                          const int* __restrict__ rowptr, const int* __restrict__ csrc,
                          const float* __restrict__ cw) {
    int t = blockIdx.x * 256 + threadIdx.x;   // grid sized exactly NN*128
    int v = t >> 7, j = t & 127;
    v = __builtin_amdgcn_readfirstlane(v);    // force scalar rowptr/csr loads
    int s = rowptr[v], e = rowptr[v + 1];
    float a0 = 0.f, a1 = 0.f;
    int i = s;
    for (; i + 3 < e; i += 4) {
        int i0 = csrc[i], i1 = csrc[i + 1], i2 = csrc[i + 2], i3 = csrc[i + 3];
        float w0 = cw[i], w1 = cw[i + 1], w2 = cw[i + 2], w3 = cw[i + 3];
        a0 += w0 * hin[(size_t)i0 * 128 + j];
        a1 += w1 * hin[(size_t)i1 * 128 + j];
        a0 += w2 * hin[(size_t)i2 * 128 + j];
        a1 += w3 * hin[(size_t)i3 * 128 + j];
    }
    for (; i < e; ++i)
        a0 += cw[i] * hin[(size_t)csrc[i] * 128 + j];
    hout[(size_t)v * 128 + j] = a0 + a1;
}

// ---------------------------------------------------------------------------
// Dense GEMMs: W column held in VGPRs, h row via (uniform) scalar loads
// ---------------------------------------------------------------------------

// acc[v][j] (=|+=) h[v][:] @ W[:,j] (+ bias) (relu) ; W is [128][128] row-major
template <int INIT, int RELU>
__global__ __launch_bounds__(128) void gemm128_k(
    const float* __restrict__ h, const float* __restrict__ W,
    const float* __restrict__ bias, float* __restrict__ acc) {
    int j = threadIdx.x;
    float wreg[128];
#pragma unroll
    for (int f = 0; f < 128; ++f) wreg[f] = W[f * 128 + j];
    float bj = INIT ? bias[j] : 0.f;
    for (int v = blockIdx.x; v < NN; v += gridDim.x) {
        const float* __restrict__ hv = h + (size_t)v * 128;
        float s0 = 0.f, s1 = 0.f, s2 = 0.f, s3 = 0.f;
#pragma unroll
        for (int f = 0; f < 128; f += 4) {
            s0 += hv[f + 0] * wreg[f + 0];
            s1 += hv[f + 1] * wreg[f + 1];
            s2 += hv[f + 2] * wreg[f + 2];
            s3 += hv[f + 3] * wreg[f + 3];
        }
        float r = (s0 + s1) + (s2 + s3);
        r += INIT ? bj : acc[(size_t)v * 128 + j];
        if (RELU) r = fmaxf(r, 0.f);
        acc[(size_t)v * 128 + j] = r;
    }
}

// Layer 0 fused: out[v][j] = relu(b0[j] + sum_k hk[v][:16] @ W0[k][:,j])
// W0cat is [64][128] (k-major), hk in {x, p1, p2, p3}
__global__ __launch_bounds__(128) void gemm64_k(
    const float* __restrict__ x, const float* __restrict__ p1,
    const float* __restrict__ p2, const float* __restrict__ p3,
    const float* __restrict__ W, const float* __restrict__ bias,
    float* __restrict__ out) {
    int j = threadIdx.x;
    float wreg[64];
#pragma unroll
    for (int f = 0; f < 64; ++f) wreg[f] = W[f * 128 + j];
    float bj = bias[j];
    for (int v = blockIdx.x; v < NN; v += gridDim.x) {
        const float* __restrict__ a = x + (size_t)v * 16;
        const float* __restrict__ b = p1 + (size_t)v * 16;
        const float* __restrict__ c = p2 + (size_t)v * 16;
        const float* __restrict__ d = p3 + (size_t)v * 16;
        float s0 = bj, s1 = 0.f, s2 = 0.f, s3 = 0.f;
#pragma unroll
        for (int f = 0; f < 16; ++f) {
            s0 += a[f] * wreg[f];
            s1 += b[f] * wreg[16 + f];
            s2 += c[f] * wreg[32 + f];
            s3 += d[f] * wreg[48 + f];
        }
        out[(size_t)v * 128 + j] = fmaxf((s0 + s1) + (s2 + s3), 0.f);
    }
}

// Final fc: out[v][0..3] = bfc + h[v][:] @ Wfc[128][4]
__global__ void fc_k(const float* __restrict__ h, const float* __restrict__ Wfc,
                     const float* __restrict__ bfc, float* __restrict__ out) {
    int t = blockIdx.x * 256 + threadIdx.x;   // grid exactly NN*128
    int v = t >> 7, j = t & 127;
    float hv = h[(size_t)v * 128 + j];
    float4 wf = reinterpret_cast<const float4*>(Wfc)[j];
    float p0 = hv * wf.x, p1 = hv * wf.y, p2 = hv * wf.z, p3 = hv * wf.w;
#pragma unroll
    for (int off = 32; off; off >>= 1) {
        p0 += __shfl_xor(p0, off);
        p1 += __shfl_xor(p1, off);
        p2 += __shfl_xor(p2, off);
        p3 += __shfl_xor(p3, off);
    }
    __shared__ float sm[2][2][4];
    int g = threadIdx.x >> 7;          // node within block
    int wn = (threadIdx.x >> 6) & 1;   // wave within node
    if ((threadIdx.x & 63) == 0) {
        sm[g][wn][0] = p0; sm[g][wn][1] = p1; sm[g][wn][2] = p2; sm[g][wn][3] = p3;
    }
    __syncthreads();
    if (threadIdx.x < 8) {
        int gg = threadIdx.x >> 2, o = threadIdx.x & 3;
        int vv = blockIdx.x * 2 + gg;
        out[(size_t)vv * 4 + o] = bfc[o] + sm[gg][0][o] + sm[gg][1][o];
    }
}

// ---------------------------------------------------------------------------

extern "C" void kernel_launch(void* const* d_in, const int* in_sizes, int n_in,
                              void* d_out, int out_size, void* d_ws, size_t ws_size,
                              hipStream_t stream) {
    const float* x    = (const float*)d_in[0];
    const int*   ei   = (const int*)d_in[1];      // [2][E] int32
    const float* ea   = (const float*)d_in[2];    // [E]
    const float* W0   = (const float*)d_in[3];    // [4][16][128]
    const float* b0   = (const float*)d_in[4];
    const float* W1   = (const float*)d_in[5];    // [4][128][128]
    const float* b1   = (const float*)d_in[6];
    const float* W2   = (const float*)d_in[7];
    const float* b2   = (const float*)d_in[8];
    const float* Wfc  = (const float*)d_in[9];    // [128][4]
    const float* bfc  = (const float*)d_in[10];
    float* out = (float*)d_out;

    const int* row = ei;
    const int* col = ei + NE;

    // ws layout (256B aligned chunks). deg and cursor adjacent for one memset.
    char* w = (char*)d_ws;
    size_t off = 0;
    auto alloc = [&](size_t bytes) {
        size_t o = off;
        off += (bytes + 255) & ~(size_t)255;
        return (void*)(w + o);
    };
    float* deg    = (float*)alloc((size_t)NN * 4);
    int*   cursor = (int*)  alloc((size_t)NN * 4);
    size_t zero_bytes = off;                       // deg + cursor
    int*   rowptr = (int*)  alloc((size_t)(NN + 1) * 4);
    int*   blksum = (int*)  alloc(512 * 4);
    int*   csrc   = (int*)  alloc((size_t)NE * 4);
    float* cw     = (float*)alloc((size_t)NE * 4);
    float* P1     = (float*)alloc((size_t)NN * 16 * 4);
    float* P2     = (float*)alloc((size_t)NN * 16 * 4);
    float* P3     = (float*)alloc((size_t)NN * 16 * 4);
    float* HA     = (float*)alloc((size_t)NN * 128 * 4);
    float* HB     = (float*)alloc((size_t)NN * 128 * 4);
    float* HC     = (float*)alloc((size_t)NN * 128 * 4);
    (void)ws_size; // requires ~187 MB

    const int nScanB = (NN + 255) / 256;  // 391

    hipMemsetAsync(d_ws, 0, zero_bytes, stream);
    deg_count_k<<<2048, 256, 0, stream>>>(col, ea, deg, cursor);
    dis_k<<<nScanB, 256, 0, stream>>>(deg);
    scan1_k<<<nScanB, 256, 0, stream>>>(cursor, rowptr, blksum);
    scan2_k<<<1, 512, 0, stream>>>(blksum, nScanB);
    scan3_k<<<nScanB, 256, 0, stream>>>(rowptr, cursor, blksum);
    scatter_k<<<2048, 256, 0, stream>>>(row, col, ea, deg, cursor, csrc, cw);

    // Layer 0 (16-dim props, fused 4-hop GEMM 64->128), output -> HA
    prop16_k<<<NN * 16 / 256, 256, 0, stream>>>(x,  P1, rowptr, csrc, cw);
    prop16_k<<<NN * 16 / 256, 256, 0, stream>>>(P1, P2, rowptr, csrc, cw);
    prop16_k<<<NN * 16 / 256, 256, 0, stream>>>(P2, P3, rowptr, csrc, cw);
    gemm64_k<<<2048, 128, 0, stream>>>(x, P1, P2, P3, W0, b0, HA);

    // Layer 1: in HA, acc HC, scratch HB
    gemm128_k<1, 0><<<4096, 128, 0, stream>>>(HA, W1,          b1, HC);
    prop128_k<<<NN * 128 / 256, 256, 0, stream>>>(HA, HB, rowptr, csrc, cw);
    gemm128_k<0, 0><<<4096, 128, 0, stream>>>(HB, W1 + 16384,  b1, HC);
    prop128_k<<<NN * 128 / 256, 256, 0, stream>>>(HB, HA, rowptr, csrc, cw);
    gemm128_k<0, 0><<<4096, 128, 0, stream>>>(HA, W1 + 32768,  b1, HC);
    prop128_k<<<NN * 128 / 256, 256, 0, stream>>>(HA, HB, rowptr, csrc, cw);
    gemm128_k<0, 1><<<4096, 128, 0, stream>>>(HB, W1 + 49152,  b1, HC);

    // Layer 2: in HC, acc HB, scratch HA (+ reuse HC)
    gemm128_k<1, 0><<<4096, 128, 0, stream>>>(HC, W2,          b2, HB);
    prop128_k<<<NN * 128 / 256, 256, 0, stream>>>(HC, HA, rowptr, csrc, cw);
    gemm128_k<0, 0><<<4096, 128, 0, stream>>>(HA, W2 + 16384,  b2, HB);
    prop128_k<<<NN * 128 / 256, 256, 0, stream>>>(HA, HC, rowptr, csrc, cw);
    gemm128_k<0, 0><<<4096, 128, 0, stream>>>(HC, W2 + 32768,  b2, HB);
    prop128_k<<<NN * 128 / 256, 256, 0, stream>>>(HC, HA, rowptr, csrc, cw);
    gemm128_k<0, 0><<<4096, 128, 0, stream>>>(HA, W2 + 49152,  b2, HB);

    // Final projection
    fc_k<<<NN * 128 / 256, 256, 0, stream>>>(HB, Wfc, bfc, out);
}

// Round 2
// 1729.030 us; speedup vs baseline: 1.1054x; 1.1054x over previous
//
#include <hip/hip_runtime.h>
#include <cstddef>
#include <cstdint>

// Problem constants (from reference)
#define NN 100000
#define NE 1600000
// F_IN=16, HID=128, OUT=4, K=3

// ---------------------------------------------------------------------------
// Graph preprocessing (atomic-light CSR build)
// ---------------------------------------------------------------------------

// rank[e] = running count of edges with same destination (1 atomic per edge)
__global__ void count_k(const int* __restrict__ col, int* __restrict__ cnt,
                        int* __restrict__ rank) {
    int e = blockIdx.x * 256 + threadIdx.x;   // grid exactly NE/256
    int c = col[e];
    rank[e] = atomicAdd(&cnt[c], 1);
}

// Block-wise exclusive scan (Hillis-Steele in LDS), 256/block
__global__ void scan1_k(const int* __restrict__ cnt, int* __restrict__ exc,
                        int* __restrict__ blksum) {
    __shared__ int sm[256];
    int i = blockIdx.x * 256 + threadIdx.x;
    int v = (i < NN) ? cnt[i] : 0;
    sm[threadIdx.x] = v;
    __syncthreads();
    for (int off = 1; off < 256; off <<= 1) {
        int t = (threadIdx.x >= off) ? sm[threadIdx.x - off] : 0;
        __syncthreads();
        sm[threadIdx.x] += t;
        __syncthreads();
    }
    if (i < NN) exc[i] = sm[threadIdx.x] - v;   // exclusive within block
    if (threadIdx.x == 255) blksum[blockIdx.x] = sm[255];
}

// Exclusive scan of block sums (nb <= 512), single block of 512
__global__ void scan2_k(int* __restrict__ blksum, int nb) {
    __shared__ int sm[512];
    int t = threadIdx.x;
    int v = (t < nb) ? blksum[t] : 0;
    sm[t] = v;
    __syncthreads();
    for (int off = 1; off < 512; off <<= 1) {
        int x = (t >= off) ? sm[t - off] : 0;
        __syncthreads();
        sm[t] += x;
        __syncthreads();
    }
    if (t < nb) blksum[t] = sm[t] - v;          // exclusive
}

// rowptr[i] += block offset; rowptr[NN] = NE
__global__ void scan3_k(int* __restrict__ rowptr, const int* __restrict__ blksum) {
    int i = blockIdx.x * 256 + threadIdx.x;
    if (i < NN) rowptr[i] += blksum[blockIdx.x];
    if (i == 0) rowptr[NN] = NE;
}

// Scatter edges into CSR-by-destination, no atomics: one 8B store per edge
__global__ void scatter_k(const int* __restrict__ row, const int* __restrict__ col,
                          const float* __restrict__ ew, const int* __restrict__ rowptr,
                          const int* __restrict__ rank, int2* __restrict__ epair) {
    int e = blockIdx.x * 256 + threadIdx.x;   // grid exactly NE/256
    int c = col[e];
    int p = rowptr[c] + rank[e];
    int2 pr;
    pr.x = row[e];
    pr.y = __float_as_int(ew[e]);
    epair[p] = pr;
}

// dis[v] = (deg>0) ? 1/sqrt(deg) : 0, deg = sum of raw weights in CSR range
__global__ void dis_k(const int* __restrict__ rowptr, const int2* __restrict__ epair,
                      float* __restrict__ dis) {
    int v = blockIdx.x * 256 + threadIdx.x;
    if (v >= NN) return;
    int s = rowptr[v], e = rowptr[v + 1];
    float d = 0.f;
    for (int i = s; i < e; ++i) d += __int_as_float(epair[i].y);
    dis[v] = (d > 0.f) ? (1.0f / sqrtf(d)) : 0.f;
}

// epair[i].w = dis[src] * w * dis[v]  (in place, 4B stores into .y only)
__global__ void norm_k(const int* __restrict__ rowptr, const float* __restrict__ dis,
                       int2* __restrict__ epair) {
    int v = blockIdx.x * 256 + threadIdx.x;
    if (v >= NN) return;
    float dv = dis[v];
    int s = rowptr[v], e = rowptr[v + 1];
    int* ey = (int*)epair;
    for (int i = s; i < e; ++i) {
        int2 p = epair[i];
        float w = dis[p.x] * __int_as_float(p.y) * dv;
        ey[2 * i + 1] = __float_as_int(w);
    }
}

// ---------------------------------------------------------------------------
// Propagation: hout[v][:] = sum_{e: col=v} norm_e * hin[src_e][:]
// ---------------------------------------------------------------------------

// 16-wide features: 4 lanes per node, float4 each
__global__ void prop16_k(const float* __restrict__ hin, float* __restrict__ hout,
                         const int* __restrict__ rowptr, const int2* __restrict__ epair) {
    int t = blockIdx.x * 256 + threadIdx.x;
    int v = t >> 2, q = t & 3;
    if (v >= NN) return;
    int s = rowptr[v], e = rowptr[v + 1];
    float4 acc = make_float4(0.f, 0.f, 0.f, 0.f);
    for (int i = s; i < e; ++i) {
        int2 p = epair[i];
        float w = __int_as_float(p.y);
        float4 h = *reinterpret_cast<const float4*>(hin + (size_t)p.x * 16 + q * 4);
        acc.x += w * h.x; acc.y += w * h.y; acc.z += w * h.z; acc.w += w * h.w;
    }
    *reinterpret_cast<float4*>(hout + (size_t)v * 16 + q * 4) = acc;
}

// 128-wide features: ONE wave per node, float2 per lane; CSR loads scalarize
__global__ __launch_bounds__(256) void prop128_k(
    const float* __restrict__ hin, float* __restrict__ hout,
    const int* __restrict__ rowptr, const int2* __restrict__ epair) {
    int wid = (blockIdx.x * 256 + threadIdx.x) >> 6;   // node, grid = NN*64/256
    int lane = threadIdx.x & 63;
    int v = __builtin_amdgcn_readfirstlane(wid);
    int s = rowptr[v], e = rowptr[v + 1];
    const float* __restrict__ hb = hin + lane * 2;
    float a0x = 0.f, a0y = 0.f, a1x = 0.f, a1y = 0.f;
    int i = s;
    for (; i + 1 < e; i += 2) {
        int2 p0 = epair[i];
        int2 p1 = epair[i + 1];
        float2 h0 = *reinterpret_cast<const float2*>(hb + (size_t)p0.x * 128);
        float2 h1 = *reinterpret_cast<const float2*>(hb + (size_t)p1.x * 128);
        float w0 = __int_as_float(p0.y), w1 = __int_as_float(p1.y);
        a0x += w0 * h0.x; a0y += w0 * h0.y;
        a1x += w1 * h1.x; a1y += w1 * h1.y;
    }
    if (i < e) {
        int2 p0 = epair[i];
        float2 h0 = *reinterpret_cast<const float2*>(hb + (size_t)p0.x * 128);
        float w0 = __int_as_float(p0.y);
        a0x += w0 * h0.x; a0y += w0 * h0.y;
    }
    float2 r;
    r.x = a0x + a1x;
    r.y = a0y + a1y;
    *reinterpret_cast<float2*>(hout + (size_t)v * 128 + lane * 2) = r;
}

// ---------------------------------------------------------------------------
// Dense GEMMs: W column held in VGPRs, h row via (uniform) scalar loads
// ---------------------------------------------------------------------------

// acc[v][j] (=|+=) h[v][:] @ W[:,j] (+ bias) (relu) ; W is [128][128] row-major
template <int INIT, int RELU>
__global__ __launch_bounds__(128) void gemm128_k(
    const float* __restrict__ h, const float* __restrict__ W,
    const float* __restrict__ bias, float* __restrict__ acc) {
    int j = threadIdx.x;
    float wreg[128];
#pragma unroll
    for (int f = 0; f < 128; ++f) wreg[f] = W[f * 128 + j];
    float bj = INIT ? bias[j] : 0.f;
    for (int v = blockIdx.x; v < NN; v += gridDim.x) {
        const float* __restrict__ hv = h + (size_t)v * 128;
        float s0 = 0.f, s1 = 0.f, s2 = 0.f, s3 = 0.f;
#pragma unroll
        for (int f = 0; f < 128; f += 4) {
            s0 += hv[f + 0] * wreg[f + 0];
            s1 += hv[f + 1] * wreg[f + 1];
            s2 += hv[f + 2] * wreg[f + 2];
            s3 += hv[f + 3] * wreg[f + 3];
        }
        float r = (s0 + s1) + (s2 + s3);
        r += INIT ? bj : acc[(size_t)v * 128 + j];
        if (RELU) r = fmaxf(r, 0.f);
        acc[(size_t)v * 128 + j] = r;
    }
}

// Layer 0 fused: out[v][j] = relu(b0[j] + sum_k hk[v][:16] @ W0[k][:,j])
__global__ __launch_bounds__(128) void gemm64_k(
    const float* __restrict__ x, const float* __restrict__ p1,
    const float* __restrict__ p2, const float* __restrict__ p3,
    const float* __restrict__ W, const float* __restrict__ bias,
    float* __restrict__ out) {
    int j = threadIdx.x;
    float wreg[64];
#pragma unroll
    for (int f = 0; f < 64; ++f) wreg[f] = W[f * 128 + j];
    float bj = bias[j];
    for (int v = blockIdx.x; v < NN; v += gridDim.x) {
        const float* __restrict__ a = x + (size_t)v * 16;
        const float* __restrict__ b = p1 + (size_t)v * 16;
        const float* __restrict__ c = p2 + (size_t)v * 16;
        const float* __restrict__ d = p3 + (size_t)v * 16;
        float s0 = bj, s1 = 0.f, s2 = 0.f, s3 = 0.f;
#pragma unroll
        for (int f = 0; f < 16; ++f) {
            s0 += a[f] * wreg[f];
            s1 += b[f] * wreg[16 + f];
            s2 += c[f] * wreg[32 + f];
            s3 += d[f] * wreg[48 + f];
        }
        out[(size_t)v * 128 + j] = fmaxf((s0 + s1) + (s2 + s3), 0.f);
    }
}

// Final fc: out[v][0..3] = bfc + h[v][:] @ Wfc[128][4]
__global__ void fc_k(const float* __restrict__ h, const float* __restrict__ Wfc,
                     const float* __restrict__ bfc, float* __restrict__ out) {
    int t = blockIdx.x * 256 + threadIdx.x;   // grid exactly NN*128/256
    int v = t >> 7, j = t & 127;
    float hv = h[(size_t)v * 128 + j];
    float4 wf = reinterpret_cast<const float4*>(Wfc)[j];
    float p0 = hv * wf.x, p1 = hv * wf.y, p2 = hv * wf.z, p3 = hv * wf.w;
#pragma unroll
    for (int off = 32; off; off >>= 1) {
        p0 += __shfl_xor(p0, off);
        p1 += __shfl_xor(p1, off);
        p2 += __shfl_xor(p2, off);
        p3 += __shfl_xor(p3, off);
    }
    __shared__ float sm[2][2][4];
    int g = threadIdx.x >> 7;          // node within block
    int wn = (threadIdx.x >> 6) & 1;   // wave within node
    if ((threadIdx.x & 63) == 0) {
        sm[g][wn][0] = p0; sm[g][wn][1] = p1; sm[g][wn][2] = p2; sm[g][wn][3] = p3;
    }
    __syncthreads();
    if (threadIdx.x < 8) {
        int gg = threadIdx.x >> 2, o = threadIdx.x & 3;
        int vv = blockIdx.x * 2 + gg;
        out[(size_t)vv * 4 + o] = bfc[o] + sm[gg][0][o] + sm[gg][1][o];
    }
}

// ---------------------------------------------------------------------------

extern "C" void kernel_launch(void* const* d_in, const int* in_sizes, int n_in,
                              void* d_out, int out_size, void* d_ws, size_t ws_size,
                              hipStream_t stream) {
    const float* x    = (const float*)d_in[0];
    const int*   ei   = (const int*)d_in[1];      // [2][E] int32
    const float* ea   = (const float*)d_in[2];    // [E]
    const float* W0   = (const float*)d_in[3];    // [4][16][128]
    const float* b0   = (const float*)d_in[4];
    const float* W1   = (const float*)d_in[5];    // [4][128][128]
    const float* b1   = (const float*)d_in[6];
    const float* W2   = (const float*)d_in[7];
    const float* b2   = (const float*)d_in[8];
    const float* Wfc  = (const float*)d_in[9];    // [128][4]
    const float* bfc  = (const float*)d_in[10];
    float* out = (float*)d_out;

    const int* row = ei;
    const int* col = ei + NE;

    // ws layout (256B aligned chunks)
    char* w = (char*)d_ws;
    size_t off = 0;
    auto alloc = [&](size_t bytes) {
        size_t o = off;
        off += (bytes + 255) & ~(size_t)255;
        return (void*)(w + o);
    };
    int*   cnt    = (int*)  alloc((size_t)NN * 4);       // must be first (memset)
    size_t zero_bytes = off;
    int*   rowptr = (int*)  alloc((size_t)(NN + 1) * 4);
    int*   blksum = (int*)  alloc(512 * 4);
    float* dis    = (float*)alloc((size_t)NN * 4);
    int2*  epair  = (int2*) alloc((size_t)NE * 8);
    float* P1     = (float*)alloc((size_t)NN * 16 * 4);
    float* P2     = (float*)alloc((size_t)NN * 16 * 4);
    float* P3     = (float*)alloc((size_t)NN * 16 * 4);
    float* HA     = (float*)alloc((size_t)NN * 128 * 4);
    float* HB     = (float*)alloc((size_t)NN * 128 * 4);
    float* HC     = (float*)alloc((size_t)NN * 128 * 4);
    int*   rank   = (int*)HA;   // alias: rank dead before HA first written
    (void)ws_size; // ~187 MB

    const int nScanB = (NN + 255) / 256;  // 391
    const int nEdgeB = NE / 256;          // 6250

    hipMemsetAsync(cnt, 0, zero_bytes, stream);
    count_k<<<nEdgeB, 256, 0, stream>>>(col, cnt, rank);
    scan1_k<<<nScanB, 256, 0, stream>>>(cnt, rowptr, blksum);
    scan2_k<<<1, 512, 0, stream>>>(blksum, nScanB);
    scan3_k<<<nScanB, 256, 0, stream>>>(rowptr, blksum);
    scatter_k<<<nEdgeB, 256, 0, stream>>>(row, col, ea, rowptr, rank, epair);
    dis_k<<<nScanB, 256, 0, stream>>>(rowptr, epair, dis);
    norm_k<<<nScanB, 256, 0, stream>>>(rowptr, dis, epair);

    // Layer 0 (16-dim props, fused 4-hop GEMM 64->128), output -> HA
    const int n16B = (NN * 4 + 255) / 256;
    prop16_k<<<n16B, 256, 0, stream>>>(x,  P1, rowptr, epair);
    prop16_k<<<n16B, 256, 0, stream>>>(P1, P2, rowptr, epair);
    prop16_k<<<n16B, 256, 0, stream>>>(P2, P3, rowptr, epair);
    gemm64_k<<<2048, 128, 0, stream>>>(x, P1, P2, P3, W0, b0, HA);

    const int nPropB = NN * 64 / 256;   // 25000 (one wave per node)

    // Layer 1: in HA, acc HC, scratch HB
    gemm128_k<1, 0><<<4096, 128, 0, stream>>>(HA, W1,          b1, HC);
    prop128_k<<<nPropB, 256, 0, stream>>>(HA, HB, rowptr, epair);
    gemm128_k<0, 0><<<4096, 128, 0, stream>>>(HB, W1 + 16384,  b1, HC);
    prop128_k<<<nPropB, 256, 0, stream>>>(HB, HA, rowptr, epair);
    gemm128_k<0, 0><<<4096, 128, 0, stream>>>(HA, W1 + 32768,  b1, HC);
    prop128_k<<<nPropB, 256, 0, stream>>>(HA, HB, rowptr, epair);
    gemm128_k<0, 1><<<4096, 128, 0, stream>>>(HB, W1 + 49152,  b1, HC);

    // Layer 2: in HC, acc HB, scratch HA/HC
    gemm128_k<1, 0><<<4096, 128, 0, stream>>>(HC, W2,          b2, HB);
    prop128_k<<<nPropB, 256, 0, stream>>>(HC, HA, rowptr, epair);
    gemm128_k<0, 0><<<4096, 128, 0, stream>>>(HA, W2 + 16384,  b2, HB);
    prop128_k<<<nPropB, 256, 0, stream>>>(HA, HC, rowptr, epair);
    gemm128_k<0, 0><<<4096, 128, 0, stream>>>(HC, W2 + 32768,  b2, HB);
    prop128_k<<<nPropB, 256, 0, stream>>>(HC, HA, rowptr, epair);
    gemm128_k<0, 0><<<4096, 128, 0, stream>>>(HA, W2 + 49152,  b2, HB);

    // Final projection
    fc_k<<<NN * 128 / 256, 256, 0, stream>>>(HB, Wfc, bfc, out);
}

// Round 3
// 879.634 us; speedup vs baseline: 2.1728x; 1.9656x over previous
//
#include <hip/hip_runtime.h>
#include <cstddef>
#include <cstdint>

// Problem constants (from reference)
#define NN 100000
#define NE 1600000
// F_IN=16, HID=128, OUT=4, K=3

typedef unsigned short u16;
using short8 = __attribute__((ext_vector_type(8))) short;  // 8 bf16 (4 VGPRs)
using f32x4  = __attribute__((ext_vector_type(4))) float;  // MFMA accum

// bf16 helpers (round-to-nearest-even via bit trick)
__device__ inline u16 f2bf(float f) {
    unsigned u = __float_as_uint(f);
    unsigned r = u + 0x7fffu + ((u >> 16) & 1u);
    return (u16)(r >> 16);
}
__device__ inline float bflo(unsigned u) { return __uint_as_float(u << 16); }
__device__ inline float bfhi(unsigned u) { return __uint_as_float(u & 0xffff0000u); }

// ---------------------------------------------------------------------------
// Graph preprocessing (atomic-light CSR build)
// ---------------------------------------------------------------------------

__global__ void count_k(const int* __restrict__ col, int* __restrict__ cnt,
                        int* __restrict__ rank) {
    int e = blockIdx.x * 256 + threadIdx.x;   // grid exactly NE/256
    int c = col[e];
    rank[e] = atomicAdd(&cnt[c], 1);
}

__global__ void scan1_k(const int* __restrict__ cnt, int* __restrict__ exc,
                        int* __restrict__ blksum) {
    __shared__ int sm[256];
    int i = blockIdx.x * 256 + threadIdx.x;
    int v = (i < NN) ? cnt[i] : 0;
    sm[threadIdx.x] = v;
    __syncthreads();
    for (int off = 1; off < 256; off <<= 1) {
        int t = (threadIdx.x >= off) ? sm[threadIdx.x - off] : 0;
        __syncthreads();
        sm[threadIdx.x] += t;
        __syncthreads();
    }
    if (i < NN) exc[i] = sm[threadIdx.x] - v;
    if (threadIdx.x == 255) blksum[blockIdx.x] = sm[255];
}

__global__ void scan2_k(int* __restrict__ blksum, int nb) {
    __shared__ int sm[512];
    int t = threadIdx.x;
    int v = (t < nb) ? blksum[t] : 0;
    sm[t] = v;
    __syncthreads();
    for (int off = 1; off < 512; off <<= 1) {
        int x = (t >= off) ? sm[t - off] : 0;
        __syncthreads();
        sm[t] += x;
        __syncthreads();
    }
    if (t < nb) blksum[t] = sm[t] - v;
}

__global__ void scan3_k(int* __restrict__ rowptr, const int* __restrict__ blksum) {
    int i = blockIdx.x * 256 + threadIdx.x;
    if (i < NN) rowptr[i] += blksum[blockIdx.x];
    if (i == 0) rowptr[NN] = NE;
}

__global__ void scatter_k(const int* __restrict__ row, const int* __restrict__ col,
                          const float* __restrict__ ew, const int* __restrict__ rowptr,
                          const int* __restrict__ rank, int2* __restrict__ epair) {
    int e = blockIdx.x * 256 + threadIdx.x;
    int c = col[e];
    int p = rowptr[c] + rank[e];
    int2 pr;
    pr.x = row[e];
    pr.y = __float_as_int(ew[e]);
    epair[p] = pr;
}

__global__ void dis_k(const int* __restrict__ rowptr, const int2* __restrict__ epair,
                      float* __restrict__ dis) {
    int v = blockIdx.x * 256 + threadIdx.x;
    if (v >= NN) return;
    int s = rowptr[v], e = rowptr[v + 1];
    float d = 0.f;
    for (int i = s; i < e; ++i) d += __int_as_float(epair[i].y);
    dis[v] = (d > 0.f) ? (1.0f / sqrtf(d)) : 0.f;
}

__global__ void norm_k(const int* __restrict__ rowptr, const float* __restrict__ dis,
                       int2* __restrict__ epair) {
    int v = blockIdx.x * 256 + threadIdx.x;
    if (v >= NN) return;
    float dv = dis[v];
    int s = rowptr[v], e = rowptr[v + 1];
    int* ey = (int*)epair;
    for (int i = s; i < e; ++i) {
        int2 p = epair[i];
        float w = dis[p.x] * __int_as_float(p.y) * dv;
        ey[2 * i + 1] = __float_as_int(w);
    }
}

// ---------------------------------------------------------------------------
// Weight prep: Wt[j][k] = bf16(W[k][j]);  W is [K][128] fp32, Wt is [128][K]
// ---------------------------------------------------------------------------
template <int K>
__global__ void wt_k(const float* __restrict__ W, u16* __restrict__ Wt) {
    int id = blockIdx.x * 256 + threadIdx.x;   // grid = 128*K/256
    int j = id / K, k = id % K;
    Wt[(size_t)j * K + k] = f2bf(W[(size_t)k * 128 + j]);
}

// ---------------------------------------------------------------------------
// Propagation
// ---------------------------------------------------------------------------

// 16-wide fp32 features (layer-0 hops): 4 lanes per node, float4 each
__global__ void prop16_k(const float* __restrict__ hin, float* __restrict__ hout,
                         const int* __restrict__ rowptr, const int2* __restrict__ epair) {
    int t = blockIdx.x * 256 + threadIdx.x;
    int v = t >> 2, q = t & 3;
    if (v >= NN) return;
    int s = rowptr[v], e = rowptr[v + 1];
    float4 acc = make_float4(0.f, 0.f, 0.f, 0.f);
    for (int i = s; i < e; ++i) {
        int2 p = epair[i];
        float w = __int_as_float(p.y);
        float4 h = *reinterpret_cast<const float4*>(hin + (size_t)p.x * 16 + q * 4);
        acc.x += w * h.x; acc.y += w * h.y; acc.z += w * h.z; acc.w += w * h.w;
    }
    *reinterpret_cast<float4*>(hout + (size_t)v * 16 + q * 4) = acc;
}

// Pack x,P1,P2,P3 (fp32 [NN][16] each) -> Xcat bf16 [NN][64]
__global__ void pack_k(const float* __restrict__ x, const float* __restrict__ p1,
                       const float* __restrict__ p2, const float* __restrict__ p3,
                       u16* __restrict__ Xcat) {
    int id = blockIdx.x * 256 + threadIdx.x;
    if (id >= NN * 4) return;
    int v = id >> 2, s = id & 3;
    const float* src = (s == 0 ? x : s == 1 ? p1 : s == 2 ? p2 : p3) + (size_t)v * 16;
    unsigned* dst = (unsigned*)(Xcat + (size_t)v * 64 + s * 16);
#pragma unroll
    for (int f = 0; f < 8; ++f) {
        dst[f] = (unsigned)f2bf(src[2 * f]) | ((unsigned)f2bf(src[2 * f + 1]) << 16);
    }
}

// 128-wide bf16 features in a stride-512 concat buffer: ONE wave per node.
// hin/hout point at slice base (Hcat + slice*128); rows are 512 u16 apart.
__global__ __launch_bounds__(256) void propbf_k(
    const u16* __restrict__ hin, u16* __restrict__ hout,
    const int* __restrict__ rowptr, const int2* __restrict__ epair) {
    int wid = (blockIdx.x * 256 + threadIdx.x) >> 6;   // grid = NN*64/256
    int lane = threadIdx.x & 63;
    int v = __builtin_amdgcn_readfirstlane(wid);
    int s = rowptr[v], e = rowptr[v + 1];
    const u16* __restrict__ hb = hin + lane * 2;
    float ax0 = 0.f, ay0 = 0.f, ax1 = 0.f, ay1 = 0.f;
    int i = s;
    for (; i + 1 < e; i += 2) {
        int2 p0 = epair[i];
        int2 p1 = epair[i + 1];
        unsigned u0 = *(const unsigned*)(hb + (size_t)p0.x * 512);
        unsigned u1 = *(const unsigned*)(hb + (size_t)p1.x * 512);
        float w0 = __int_as_float(p0.y), w1 = __int_as_float(p1.y);
        ax0 += w0 * bflo(u0); ay0 += w0 * bfhi(u0);
        ax1 += w1 * bflo(u1); ay1 += w1 * bfhi(u1);
    }
    if (i < e) {
        int2 p0 = epair[i];
        unsigned u0 = *(const unsigned*)(hb + (size_t)p0.x * 512);
        float w0 = __int_as_float(p0.y);
        ax0 += w0 * bflo(u0); ay0 += w0 * bfhi(u0);
    }
    unsigned o = (unsigned)f2bf(ax0 + ax1) | ((unsigned)f2bf(ay0 + ay1) << 16);
    *(unsigned*)(hout + (size_t)v * 512 + lane * 2) = o;
}

// ---------------------------------------------------------------------------
// MFMA GEMM: C[M=NN][128] = A[NN][K]bf16 x W[K][128] (+bias, relu)
// A row-major stride K; Bt is W transposed [128][K] bf16.
// Wave computes 32 rows x 128 cols. No LDS, no barriers.
// Frag layout (guide m89/m92): lane=16*h+r holds A[row0+r][k0+8h..+7],
// B[k0+8h..+7][j0+r] = Bt[j0+r][k0+8h..+7]; D: col=r, row=4h+i.
// ---------------------------------------------------------------------------
template <int KSTEPS, int RELU, int BF16OUT>
__global__ __launch_bounds__(256) void mgemm_k(
    const u16* __restrict__ A, const u16* __restrict__ Bt,
    const float* __restrict__ bias,
    u16* __restrict__ outb,      // bf16 out, stride 512 (slice 0), if BF16OUT
    float* __restrict__ outf) {  // fp32 out, stride 128, else
    const int K = KSTEPS * 32;
    int wid = (blockIdx.x * 256 + threadIdx.x) >> 6;
    int v0 = wid * 32;
    if (v0 >= NN) return;
    int lane = threadIdx.x & 63;
    int r = lane & 15, h = lane >> 4;
    const u16* a0p = A + (size_t)(v0 + r) * K + h * 8;
    const u16* a1p = a0p + (size_t)16 * K;
    const u16* bp  = Bt + (size_t)r * K + h * 8;
    f32x4 acc0[8] = {{0.f, 0.f, 0.f, 0.f}};
    f32x4 acc1[8] = {{0.f, 0.f, 0.f, 0.f}};
#pragma unroll
    for (int j = 0; j < 8; ++j) { acc0[j] = {0.f, 0.f, 0.f, 0.f}; acc1[j] = {0.f, 0.f, 0.f, 0.f}; }
#pragma unroll
    for (int kk = 0; kk < KSTEPS; ++kk) {
        short8 a0 = *(const short8*)(a0p + kk * 32);
        short8 a1 = *(const short8*)(a1p + kk * 32);
#pragma unroll
        for (int j = 0; j < 8; ++j) {
            short8 b = *(const short8*)(bp + (size_t)j * 16 * K + kk * 32);
            acc0[j] = __builtin_amdgcn_mfma_f32_16x16x32_bf16(a0, b, acc0[j], 0, 0, 0);
            acc1[j] = __builtin_amdgcn_mfma_f32_16x16x32_bf16(a1, b, acc1[j], 0, 0, 0);
        }
    }
#pragma unroll
    for (int j = 0; j < 8; ++j) {
        int c = j * 16 + r;
        float bj = bias[c];
#pragma unroll
        for (int i = 0; i < 4; ++i) {
            int row0 = v0 + h * 4 + i;
            int row1 = row0 + 16;
            float c0 = acc0[j][i] + bj;
            float c1 = acc1[j][i] + bj;
            if (RELU) { c0 = fmaxf(c0, 0.f); c1 = fmaxf(c1, 0.f); }
            if (BF16OUT) {
                outb[(size_t)row0 * 512 + c] = f2bf(c0);
                outb[(size_t)row1 * 512 + c] = f2bf(c1);
            } else {
                outf[(size_t)row0 * 128 + c] = c0;
                outf[(size_t)row1 * 128 + c] = c1;
            }
        }
    }
}

// Final fc: out[v][0..3] = bfc + h[v][:] @ Wfc[128][4]  (h fp32)
__global__ void fc_k(const float* __restrict__ h, const float* __restrict__ Wfc,
                     const float* __restrict__ bfc, float* __restrict__ out) {
    int t = blockIdx.x * 256 + threadIdx.x;   // grid exactly NN*128/256
    int v = t >> 7, j = t & 127;
    float hv = h[(size_t)v * 128 + j];
    float4 wf = reinterpret_cast<const float4*>(Wfc)[j];
    float p0 = hv * wf.x, p1 = hv * wf.y, p2 = hv * wf.z, p3 = hv * wf.w;
#pragma unroll
    for (int off = 32; off; off >>= 1) {
        p0 += __shfl_xor(p0, off);
        p1 += __shfl_xor(p1, off);
        p2 += __shfl_xor(p2, off);
        p3 += __shfl_xor(p3, off);
    }
    __shared__ float sm[2][2][4];
    int g = threadIdx.x >> 7;
    int wn = (threadIdx.x >> 6) & 1;
    if ((threadIdx.x & 63) == 0) {
        sm[g][wn][0] = p0; sm[g][wn][1] = p1; sm[g][wn][2] = p2; sm[g][wn][3] = p3;
    }
    __syncthreads();
    if (threadIdx.x < 8) {
        int gg = threadIdx.x >> 2, o = threadIdx.x & 3;
        int vv = blockIdx.x * 2 + gg;
        out[(size_t)vv * 4 + o] = bfc[o] + sm[gg][0][o] + sm[gg][1][o];
    }
}

// ---------------------------------------------------------------------------

extern "C" void kernel_launch(void* const* d_in, const int* in_sizes, int n_in,
                              void* d_out, int out_size, void* d_ws, size_t ws_size,
                              hipStream_t stream) {
    const float* x    = (const float*)d_in[0];
    const int*   ei   = (const int*)d_in[1];      // [2][E] int32
    const float* ea   = (const float*)d_in[2];    // [E]
    const float* W0   = (const float*)d_in[3];    // [4][16][128] = [64][128]
    const float* b0   = (const float*)d_in[4];
    const float* W1   = (const float*)d_in[5];    // [4][128][128] = [512][128]
    const float* b1   = (const float*)d_in[6];
    const float* W2   = (const float*)d_in[7];
    const float* b2   = (const float*)d_in[8];
    const float* Wfc  = (const float*)d_in[9];    // [128][4]
    const float* bfc  = (const float*)d_in[10];
    float* out = (float*)d_out;

    const int* row = ei;
    const int* col = ei + NE;

    // ws layout (256B aligned chunks), ~168 MB total
    char* w = (char*)d_ws;
    size_t off = 0;
    auto alloc = [&](size_t bytes) {
        size_t o = off;
        off += (bytes + 255) & ~(size_t)255;
        return (void*)(w + o);
    };
    int*   cnt    = (int*)  alloc((size_t)NN * 4);       // first (memset)
    size_t zero_bytes = off;
    int*   rowptr = (int*)  alloc((size_t)(NN + 1) * 4);
    int*   blksum = (int*)  alloc(512 * 4);
    float* dis    = (float*)alloc((size_t)NN * 4);
    int2*  epair  = (int2*) alloc((size_t)NE * 8);
    u16*   Wt0    = (u16*)  alloc((size_t)128 * 64 * 2);
    u16*   Wt1    = (u16*)  alloc((size_t)128 * 512 * 2);
    u16*   Wt2    = (u16*)  alloc((size_t)128 * 512 * 2);
    // union region: P1,P2,P3,Xcat live early; HF lives late (all dead between)
    char*  ureg   = (char*) alloc((size_t)NN * 128 * 4); // 51.2 MB
    float* P1   = (float*)(ureg);
    float* P2   = (float*)(ureg + (size_t)NN * 16 * 4);
    float* P3   = (float*)(ureg + (size_t)NN * 32 * 4);
    u16*   Xcat = (u16*)  (ureg + (size_t)NN * 48 * 4);
    float* HF   = (float*)(ureg);
    u16*   Hcat = (u16*)  alloc((size_t)NN * 512 * 2);   // 102.4 MB
    int*   rank = (int*)Hcat;   // alias: dead before Hcat first written
    (void)ws_size;

    const int nScanB = (NN + 255) / 256;  // 391
    const int nEdgeB = NE / 256;          // 6250
    const int nPropB = NN * 64 / 256;     // 25000 (one wave per node)
    const int nGemmB = (NN / 32 + 3) / 4; // 782  (32 rows per wave, 4 waves/blk)

    hipMemsetAsync(cnt, 0, zero_bytes, stream);
    count_k<<<nEdgeB, 256, 0, stream>>>(col, cnt, rank);
    scan1_k<<<nScanB, 256, 0, stream>>>(cnt, rowptr, blksum);
    scan2_k<<<1, 512, 0, stream>>>(blksum, nScanB);
    scan3_k<<<nScanB, 256, 0, stream>>>(rowptr, blksum);
    scatter_k<<<nEdgeB, 256, 0, stream>>>(row, col, ea, rowptr, rank, epair);
    dis_k<<<nScanB, 256, 0, stream>>>(rowptr, epair, dis);
    norm_k<<<nScanB, 256, 0, stream>>>(rowptr, dis, epair);

    // Weight transposes (bf16)
    wt_k<64> <<<32,  256, 0, stream>>>(W0, Wt0);
    wt_k<512><<<256, 256, 0, stream>>>(W1, Wt1);
    wt_k<512><<<256, 256, 0, stream>>>(W2, Wt2);

    // Layer 0: fp32 16-wide hops, pack to bf16, MFMA K=64 -> Hcat slice0
    const int n16B = (NN * 4 + 255) / 256;
    prop16_k<<<n16B, 256, 0, stream>>>(x,  P1, rowptr, epair);
    prop16_k<<<n16B, 256, 0, stream>>>(P1, P2, rowptr, epair);
    prop16_k<<<n16B, 256, 0, stream>>>(P2, P3, rowptr, epair);
    pack_k<<<n16B, 256, 0, stream>>>(x, P1, P2, P3, Xcat);
    mgemm_k<2, 1, 1><<<nGemmB, 256, 0, stream>>>(Xcat, Wt0, b0, Hcat, nullptr);

    // Layer 1: hops fill slices 1..3, fused GEMM K=512 -> slice0 (in place, relu)
    propbf_k<<<nPropB, 256, 0, stream>>>(Hcat,       Hcat + 128, rowptr, epair);
    propbf_k<<<nPropB, 256, 0, stream>>>(Hcat + 128, Hcat + 256, rowptr, epair);
    propbf_k<<<nPropB, 256, 0, stream>>>(Hcat + 256, Hcat + 384, rowptr, epair);
    mgemm_k<16, 1, 1><<<nGemmB, 256, 0, stream>>>(Hcat, Wt1, b1, Hcat, nullptr);

    // Layer 2: same, final GEMM -> HF fp32 (no relu)
    propbf_k<<<nPropB, 256, 0, stream>>>(Hcat,       Hcat + 128, rowptr, epair);
    propbf_k<<<nPropB, 256, 0, stream>>>(Hcat + 128, Hcat + 256, rowptr, epair);
    propbf_k<<<nPropB, 256, 0, stream>>>(Hcat + 256, Hcat + 384, rowptr, epair);
    mgemm_k<16, 0, 0><<<nGemmB, 256, 0, stream>>>(Hcat, Wt2, b2, nullptr, HF);

    // Final projection
    fc_k<<<NN * 128 / 256, 256, 0, stream>>>(HF, Wfc, bfc, out);
}

// Round 4
// 757.834 us; speedup vs baseline: 2.5220x; 1.1607x over previous
//
#include <hip/hip_runtime.h>
#include <cstddef>
#include <cstdint>

// Problem constants (from reference)
#define NN 100000
#define NE 1600000
// F_IN=16, HID=128, OUT=4, K=3

typedef unsigned short u16;
using short8 = __attribute__((ext_vector_type(8))) short;  // 8 bf16 (4 VGPRs)
using f32x4  = __attribute__((ext_vector_type(4))) float;  // MFMA accum

// bf16 helpers (round-to-nearest-even via bit trick)
__device__ inline u16 f2bf(float f) {
    unsigned u = __float_as_uint(f);
    unsigned r = u + 0x7fffu + ((u >> 16) & 1u);
    return (u16)(r >> 16);
}
__device__ inline float bflo(unsigned u) { return __uint_as_float(u << 16); }
__device__ inline float bfhi(unsigned u) { return __uint_as_float(u & 0xffff0000u); }

// ---------------------------------------------------------------------------
// Graph preprocessing (atomic-light CSR build)
// ---------------------------------------------------------------------------

__global__ void count_k(const int* __restrict__ col, int* __restrict__ cnt,
                        int* __restrict__ rank) {
    int e = blockIdx.x * 256 + threadIdx.x;   // grid exactly NE/256
    int c = col[e];
    rank[e] = atomicAdd(&cnt[c], 1);
}

__global__ void scan1_k(const int* __restrict__ cnt, int* __restrict__ exc,
                        int* __restrict__ blksum) {
    __shared__ int sm[256];
    int i = blockIdx.x * 256 + threadIdx.x;
    int v = (i < NN) ? cnt[i] : 0;
    sm[threadIdx.x] = v;
    __syncthreads();
    for (int off = 1; off < 256; off <<= 1) {
        int t = (threadIdx.x >= off) ? sm[threadIdx.x - off] : 0;
        __syncthreads();
        sm[threadIdx.x] += t;
        __syncthreads();
    }
    if (i < NN) exc[i] = sm[threadIdx.x] - v;
    if (threadIdx.x == 255) blksum[blockIdx.x] = sm[255];
}

__global__ void scan2_k(int* __restrict__ blksum, int nb) {
    __shared__ int sm[512];
    int t = threadIdx.x;
    int v = (t < nb) ? blksum[t] : 0;
    sm[t] = v;
    __syncthreads();
    for (int off = 1; off < 512; off <<= 1) {
        int x = (t >= off) ? sm[t - off] : 0;
        __syncthreads();
        sm[t] += x;
        __syncthreads();
    }
    if (t < nb) blksum[t] = sm[t] - v;
}

__global__ void scan3_k(int* __restrict__ rowptr, const int* __restrict__ blksum) {
    int i = blockIdx.x * 256 + threadIdx.x;
    if (i < NN) rowptr[i] += blksum[blockIdx.x];
    if (i == 0) rowptr[NN] = NE;
}

__global__ void scatter_k(const int* __restrict__ row, const int* __restrict__ col,
                          const float* __restrict__ ew, const int* __restrict__ rowptr,
                          const int* __restrict__ rank, int2* __restrict__ epair) {
    int e = blockIdx.x * 256 + threadIdx.x;
    int c = col[e];
    int p = rowptr[c] + rank[e];
    int2 pr;
    pr.x = row[e];
    pr.y = __float_as_int(ew[e]);
    epair[p] = pr;
}

__global__ void dis_k(const int* __restrict__ rowptr, const int2* __restrict__ epair,
                      float* __restrict__ dis) {
    int v = blockIdx.x * 256 + threadIdx.x;
    if (v >= NN) return;
    int s = rowptr[v], e = rowptr[v + 1];
    float d = 0.f;
    for (int i = s; i < e; ++i) d += __int_as_float(epair[i].y);
    dis[v] = (d > 0.f) ? (1.0f / sqrtf(d)) : 0.f;
}

__global__ void norm_k(const int* __restrict__ rowptr, const float* __restrict__ dis,
                       int2* __restrict__ epair) {
    int v = blockIdx.x * 256 + threadIdx.x;
    if (v >= NN) return;
    float dv = dis[v];
    int s = rowptr[v], e = rowptr[v + 1];
    int* ey = (int*)epair;
    for (int i = s; i < e; ++i) {
        int2 p = epair[i];
        float w = dis[p.x] * __int_as_float(p.y) * dv;
        ey[2 * i + 1] = __float_as_int(w);
    }
}

// ---------------------------------------------------------------------------
// Weight prep: Wt[j][k] = bf16(W[k][j]);  W is [K][128] fp32, Wt is [128][K]
// ---------------------------------------------------------------------------
template <int K>
__global__ void wt_k(const float* __restrict__ W, u16* __restrict__ Wt) {
    int id = blockIdx.x * 256 + threadIdx.x;   // grid = 128*K/256
    int j = id / K, k = id % K;
    Wt[(size_t)j * K + k] = f2bf(W[(size_t)k * 128 + j]);
}

// ---------------------------------------------------------------------------
// Propagation
// ---------------------------------------------------------------------------

// 16-wide fp32 features (layer-0 hops): 4 lanes per node, float4 each
__global__ void prop16_k(const float* __restrict__ hin, float* __restrict__ hout,
                         const int* __restrict__ rowptr, const int2* __restrict__ epair) {
    int t = blockIdx.x * 256 + threadIdx.x;
    int v = t >> 2, q = t & 3;
    if (v >= NN) return;
    int s = rowptr[v], e = rowptr[v + 1];
    float4 acc = make_float4(0.f, 0.f, 0.f, 0.f);
    for (int i = s; i < e; ++i) {
        int2 p = epair[i];
        float w = __int_as_float(p.y);
        float4 h = *reinterpret_cast<const float4*>(hin + (size_t)p.x * 16 + q * 4);
        acc.x += w * h.x; acc.y += w * h.y; acc.z += w * h.z; acc.w += w * h.w;
    }
    *reinterpret_cast<float4*>(hout + (size_t)v * 16 + q * 4) = acc;
}

// Pack x,P1,P2,P3 (fp32 [NN][16] each) -> Xcat bf16 [NN][64]
__global__ void pack_k(const float* __restrict__ x, const float* __restrict__ p1,
                       const float* __restrict__ p2, const float* __restrict__ p3,
                       u16* __restrict__ Xcat) {
    int id = blockIdx.x * 256 + threadIdx.x;
    if (id >= NN * 4) return;
    int v = id >> 2, s = id & 3;
    const float* src = (s == 0 ? x : s == 1 ? p1 : s == 2 ? p2 : p3) + (size_t)v * 16;
    unsigned* dst = (unsigned*)(Xcat + (size_t)v * 64 + s * 16);
#pragma unroll
    for (int f = 0; f < 8; ++f) {
        dst[f] = (unsigned)f2bf(src[2 * f]) | ((unsigned)f2bf(src[2 * f + 1]) << 16);
    }
}

// 128-wide bf16 features in a stride-512 concat buffer: ONE wave per node.
__global__ __launch_bounds__(256) void propbf_k(
    const u16* __restrict__ hin, u16* __restrict__ hout,
    const int* __restrict__ rowptr, const int2* __restrict__ epair) {
    int wid = (blockIdx.x * 256 + threadIdx.x) >> 6;   // grid = NN*64/256
    int lane = threadIdx.x & 63;
    int v = __builtin_amdgcn_readfirstlane(wid);
    int s = rowptr[v], e = rowptr[v + 1];
    const u16* __restrict__ hb = hin + lane * 2;
    float ax0 = 0.f, ay0 = 0.f, ax1 = 0.f, ay1 = 0.f;
    int i = s;
    for (; i + 1 < e; i += 2) {
        int2 p0 = epair[i];
        int2 p1 = epair[i + 1];
        unsigned u0 = *(const unsigned*)(hb + (size_t)p0.x * 512);
        unsigned u1 = *(const unsigned*)(hb + (size_t)p1.x * 512);
        float w0 = __int_as_float(p0.y), w1 = __int_as_float(p1.y);
        ax0 += w0 * bflo(u0); ay0 += w0 * bfhi(u0);
        ax1 += w1 * bflo(u1); ay1 += w1 * bfhi(u1);
    }
    if (i < e) {
        int2 p0 = epair[i];
        unsigned u0 = *(const unsigned*)(hb + (size_t)p0.x * 512);
        float w0 = __int_as_float(p0.y);
        ax0 += w0 * bflo(u0); ay0 += w0 * bfhi(u0);
    }
    unsigned o = (unsigned)f2bf(ax0 + ax1) | ((unsigned)f2bf(ay0 + ay1) << 16);
    *(unsigned*)(hout + (size_t)v * 512 + lane * 2) = o;
}

// ---------------------------------------------------------------------------
// MFMA GEMM v2: C[NN][128] = A[NN][K]bf16 @ W[K][128] (+bias, relu) -> bf16
// out stride 512 (slice 0 of concat buffer).
// - Bt ([128][K] bf16) staged in LDS once per block, XOR-swizzled
//   (byte ^= ((row&7)<<4)) so ds_read_b128 at 1024B row stride is
//   conflict-free (guide G4). Staged via linear LDS dest + pre-swizzled
//   global src (XOR is an involution within a row).
// - Persistent 512-thread blocks (8 waves), grid=256 (1 block/CU, LDS-bound),
//   atomic ticket over row-tiles of 256 (deterministic output: tiles pure).
// - Wave computes 32 rows x 128 cols; MFMA 16x16x32, D: col=lane&15,
//   row=(lane>>4)*4+i (guide m89).
// ---------------------------------------------------------------------------
template <int KSTEPS, int RELU>
__global__ __launch_bounds__(512, 2) void mgemm2_k(
    const u16* __restrict__ A, const u16* __restrict__ Bt,
    const float* __restrict__ bias, u16* __restrict__ outb,
    int* __restrict__ ctr, int ntiles) {
    const int K = KSTEPS * 32;
    const int BBYTES = 128 * K * 2;
    __shared__ u16 smB[128 * KSTEPS * 32];
    __shared__ int smt;
    int tid = threadIdx.x;

    // Stage B: LDS[d] = Bt[d ^ swz(row(d))]; read side applies same XOR.
    for (int d = tid * 16; d < BBYTES; d += 512 * 16) {
        int rowb = d / (K * 2);
        int src = d ^ ((rowb & 7) << 4);
        *(short8*)((char*)smB + d) = *(const short8*)((const char*)Bt + src);
    }

    int lane = tid & 63;
    int wv = tid >> 6;
    int r = lane & 15, h = lane >> 4;
    float bj[8];
#pragma unroll
    for (int j = 0; j < 8; ++j) bj[j] = bias[j * 16 + r];
    const char* bbase = (const char*)smB;

    for (;;) {
        __syncthreads();                      // covers staging + smt reuse
        if (tid == 0) smt = atomicAdd(ctr, 1);
        __syncthreads();
        int t = smt;
        if (t >= ntiles) break;               // uniform across block
        int v0 = t * 256 + wv * 32;
        if (v0 >= NN) continue;               // converges at loop-top barrier

        const u16* a0p = A + (size_t)(v0 + r) * K + h * 8;
        const u16* a1p = a0p + (size_t)16 * K;
        f32x4 acc0[8], acc1[8];
#pragma unroll
        for (int j = 0; j < 8; ++j) {
            acc0[j] = {0.f, 0.f, 0.f, 0.f};
            acc1[j] = {0.f, 0.f, 0.f, 0.f};
        }
#pragma unroll
        for (int kk = 0; kk < KSTEPS; ++kk) {
            short8 a0 = *(const short8*)(a0p + kk * 32);
            short8 a1 = *(const short8*)(a1p + kk * 32);
#pragma unroll
            for (int j = 0; j < 8; ++j) {
                int bb = ((j * 16 + r) * K * 2 + kk * 64 + h * 16) ^ ((r & 7) << 4);
                short8 b = *(const short8*)(bbase + bb);
                acc0[j] = __builtin_amdgcn_mfma_f32_16x16x32_bf16(a0, b, acc0[j], 0, 0, 0);
                acc1[j] = __builtin_amdgcn_mfma_f32_16x16x32_bf16(a1, b, acc1[j], 0, 0, 0);
            }
        }
        // Epilogue: i-outer, j-inner so 32B half-line stores are adjacent.
#pragma unroll
        for (int i = 0; i < 4; ++i) {
            int row0 = v0 + h * 4 + i;
#pragma unroll
            for (int j = 0; j < 8; ++j) {
                float c0 = acc0[j][i] + bj[j];
                float c1 = acc1[j][i] + bj[j];
                if (RELU) { c0 = fmaxf(c0, 0.f); c1 = fmaxf(c1, 0.f); }
                outb[(size_t)row0 * 512 + j * 16 + r] = f2bf(c0);
                outb[(size_t)(row0 + 16) * 512 + j * 16 + r] = f2bf(c1);
            }
        }
    }
}

// Final fc: out[v][0..3] = bfc + h[v][:] @ Wfc[128][4]; h bf16 stride 512.
// One wave per node: lane p handles cols 2p, 2p+1.
__global__ void fcb_k(const u16* __restrict__ H, const float* __restrict__ Wfc,
                      const float* __restrict__ bfc, float* __restrict__ out) {
    int t = blockIdx.x * 256 + threadIdx.x;   // grid = NN*64/256
    int v = t >> 6, p = t & 63;
    unsigned u = *(const unsigned*)(H + (size_t)v * 512 + p * 2);
    float h0 = bflo(u), h1 = bfhi(u);
    float4 w0 = reinterpret_cast<const float4*>(Wfc)[2 * p];
    float4 w1 = reinterpret_cast<const float4*>(Wfc)[2 * p + 1];
    float s0 = h0 * w0.x + h1 * w1.x;
    float s1 = h0 * w0.y + h1 * w1.y;
    float s2 = h0 * w0.z + h1 * w1.z;
    float s3 = h0 * w0.w + h1 * w1.w;
#pragma unroll
    for (int off = 32; off; off >>= 1) {
        s0 += __shfl_xor(s0, off);
        s1 += __shfl_xor(s1, off);
        s2 += __shfl_xor(s2, off);
        s3 += __shfl_xor(s3, off);
    }
    if (p == 0) {
        float4 o = make_float4(s0 + bfc[0], s1 + bfc[1], s2 + bfc[2], s3 + bfc[3]);
        reinterpret_cast<float4*>(out)[v] = o;
    }
}

// ---------------------------------------------------------------------------

extern "C" void kernel_launch(void* const* d_in, const int* in_sizes, int n_in,
                              void* d_out, int out_size, void* d_ws, size_t ws_size,
                              hipStream_t stream) {
    const float* x    = (const float*)d_in[0];
    const int*   ei   = (const int*)d_in[1];      // [2][E] int32
    const float* ea   = (const float*)d_in[2];    // [E]
    const float* W0   = (const float*)d_in[3];    // [4][16][128] = [64][128]
    const float* b0   = (const float*)d_in[4];
    const float* W1   = (const float*)d_in[5];    // [4][128][128] = [512][128]
    const float* b1   = (const float*)d_in[6];
    const float* W2   = (const float*)d_in[7];
    const float* b2   = (const float*)d_in[8];
    const float* Wfc  = (const float*)d_in[9];    // [128][4]
    const float* bfc  = (const float*)d_in[10];
    float* out = (float*)d_out;

    const int* row = ei;
    const int* col = ei + NE;

    // ws layout (256B aligned chunks)
    char* w = (char*)d_ws;
    size_t off = 0;
    auto alloc = [&](size_t bytes) {
        size_t o = off;
        off += (bytes + 255) & ~(size_t)255;
        return (void*)(w + o);
    };
    int*   cnt    = (int*)  alloc((size_t)NN * 4);       // first (memset)
    int*   ctr    = (int*)  alloc(3 * 4);                // gemm tickets
    size_t zero_bytes = off;
    int*   rowptr = (int*)  alloc((size_t)(NN + 1) * 4);
    int*   blksum = (int*)  alloc(512 * 4);
    float* dis    = (float*)alloc((size_t)NN * 4);
    int2*  epair  = (int2*) alloc((size_t)NE * 8);
    u16*   Wt0    = (u16*)  alloc((size_t)128 * 64 * 2);
    u16*   Wt1    = (u16*)  alloc((size_t)128 * 512 * 2);
    u16*   Wt2    = (u16*)  alloc((size_t)128 * 512 * 2);
    // union region: P1,P2,P3,Xcat live early only
    char*  ureg   = (char*) alloc((size_t)NN * 128 * 4); // 51.2 MB
    float* P1   = (float*)(ureg);
    float* P2   = (float*)(ureg + (size_t)NN * 16 * 4);
    float* P3   = (float*)(ureg + (size_t)NN * 32 * 4);
    u16*   Xcat = (u16*)  (ureg + (size_t)NN * 48 * 4);
    u16*   Hcat = (u16*)  alloc((size_t)NN * 512 * 2);   // 102.4 MB
    int*   rank = (int*)Hcat;   // alias: dead before Hcat first written
    (void)ws_size;

    const int nScanB = (NN + 255) / 256;  // 391
    const int nEdgeB = NE / 256;          // 6250
    const int nPropB = NN * 64 / 256;     // 25000 (one wave per node)
    const int nTiles = (NN + 255) / 256;  // 391 row-tiles of 256

    hipMemsetAsync(cnt, 0, zero_bytes, stream);
    count_k<<<nEdgeB, 256, 0, stream>>>(col, cnt, rank);
    scan1_k<<<nScanB, 256, 0, stream>>>(cnt, rowptr, blksum);
    scan2_k<<<1, 512, 0, stream>>>(blksum, nScanB);
    scan3_k<<<nScanB, 256, 0, stream>>>(rowptr, blksum);
    scatter_k<<<nEdgeB, 256, 0, stream>>>(row, col, ea, rowptr, rank, epair);
    dis_k<<<nScanB, 256, 0, stream>>>(rowptr, epair, dis);
    norm_k<<<nScanB, 256, 0, stream>>>(rowptr, dis, epair);

    // Weight transposes (bf16)
    wt_k<64> <<<32,  256, 0, stream>>>(W0, Wt0);
    wt_k<512><<<256, 256, 0, stream>>>(W1, Wt1);
    wt_k<512><<<256, 256, 0, stream>>>(W2, Wt2);

    // Layer 0: fp32 16-wide hops, pack to bf16, MFMA K=64 -> Hcat slice0
    const int n16B = (NN * 4 + 255) / 256;
    prop16_k<<<n16B, 256, 0, stream>>>(x,  P1, rowptr, epair);
    prop16_k<<<n16B, 256, 0, stream>>>(P1, P2, rowptr, epair);
    prop16_k<<<n16B, 256, 0, stream>>>(P2, P3, rowptr, epair);
    pack_k<<<n16B, 256, 0, stream>>>(x, P1, P2, P3, Xcat);
    mgemm2_k<2, 1><<<256, 512, 0, stream>>>(Xcat, Wt0, b0, Hcat, ctr + 0, nTiles);

    // Layer 1: hops fill slices 1..3, fused GEMM K=512 -> slice0 (in place)
    propbf_k<<<nPropB, 256, 0, stream>>>(Hcat,       Hcat + 128, rowptr, epair);
    propbf_k<<<nPropB, 256, 0, stream>>>(Hcat + 128, Hcat + 256, rowptr, epair);
    propbf_k<<<nPropB, 256, 0, stream>>>(Hcat + 256, Hcat + 384, rowptr, epair);
    mgemm2_k<16, 1><<<256, 512, 0, stream>>>(Hcat, Wt1, b1, Hcat, ctr + 1, nTiles);

    // Layer 2: same, final GEMM -> slice0 bf16 (no relu)
    propbf_k<<<nPropB, 256, 0, stream>>>(Hcat,       Hcat + 128, rowptr, epair);
    propbf_k<<<nPropB, 256, 0, stream>>>(Hcat + 128, Hcat + 256, rowptr, epair);
    propbf_k<<<nPropB, 256, 0, stream>>>(Hcat + 256, Hcat + 384, rowptr, epair);
    mgemm2_k<16, 0><<<256, 512, 0, stream>>>(Hcat, Wt2, b2, Hcat, ctr + 2, nTiles);

    // Final projection (reads bf16 slice0)
    fcb_k<<<nPropB, 256, 0, stream>>>(Hcat, Wfc, bfc, out);
}

// Round 5
// 682.183 us; speedup vs baseline: 2.8017x; 1.1109x over previous
//
#include <hip/hip_runtime.h>
#include <cstddef>
#include <cstdint>

// Problem constants (from reference)
#define NN 100000
#define NE 1600000
// F_IN=16, HID=128, OUT=4, K=3

typedef unsigned short u16;
using short8 = __attribute__((ext_vector_type(8))) short;  // 8 bf16 (4 VGPRs)
using f32x4  = __attribute__((ext_vector_type(4))) float;  // MFMA accum

// bf16 helpers (round-to-nearest-even via bit trick)
__device__ inline u16 f2bf(float f) {
    unsigned u = __float_as_uint(f);
    unsigned r = u + 0x7fffu + ((u >> 16) & 1u);
    return (u16)(r >> 16);
}
__device__ inline float bflo(unsigned u) { return __uint_as_float(u << 16); }
__device__ inline float bfhi(unsigned u) { return __uint_as_float(u & 0xffff0000u); }

// ---------------------------------------------------------------------------
// Graph preprocessing (atomic-light CSR build)
// ---------------------------------------------------------------------------

__global__ void count_k(const int* __restrict__ col, int* __restrict__ cnt,
                        int* __restrict__ rank) {
    int e = blockIdx.x * 256 + threadIdx.x;   // grid exactly NE/256
    int c = col[e];
    rank[e] = atomicAdd(&cnt[c], 1);
}

__global__ void scan1_k(const int* __restrict__ cnt, int* __restrict__ exc,
                        int* __restrict__ blksum) {
    __shared__ int sm[256];
    int i = blockIdx.x * 256 + threadIdx.x;
    int v = (i < NN) ? cnt[i] : 0;
    sm[threadIdx.x] = v;
    __syncthreads();
    for (int off = 1; off < 256; off <<= 1) {
        int t = (threadIdx.x >= off) ? sm[threadIdx.x - off] : 0;
        __syncthreads();
        sm[threadIdx.x] += t;
        __syncthreads();
    }
    if (i < NN) exc[i] = sm[threadIdx.x] - v;
    if (threadIdx.x == 255) blksum[blockIdx.x] = sm[255];
}

__global__ void scan2_k(int* __restrict__ blksum, int nb) {
    __shared__ int sm[512];
    int t = threadIdx.x;
    int v = (t < nb) ? blksum[t] : 0;
    sm[t] = v;
    __syncthreads();
    for (int off = 1; off < 512; off <<= 1) {
        int x = (t >= off) ? sm[t - off] : 0;
        __syncthreads();
        sm[t] += x;
        __syncthreads();
    }
    if (t < nb) blksum[t] = sm[t] - v;
}

__global__ void scan3_k(int* __restrict__ rowptr, const int* __restrict__ blksum) {
    int i = blockIdx.x * 256 + threadIdx.x;
    if (i < NN) rowptr[i] += blksum[blockIdx.x];
    if (i == 0) rowptr[NN] = NE;
}

__global__ void scatter_k(const int* __restrict__ row, const int* __restrict__ col,
                          const float* __restrict__ ew, const int* __restrict__ rowptr,
                          const int* __restrict__ rank, int2* __restrict__ epair) {
    int e = blockIdx.x * 256 + threadIdx.x;
    int c = col[e];
    int p = rowptr[c] + rank[e];
    int2 pr;
    pr.x = row[e];
    pr.y = __float_as_int(ew[e]);
    epair[p] = pr;
}

__global__ void dis_k(const int* __restrict__ rowptr, const int2* __restrict__ epair,
                      float* __restrict__ dis) {
    int v = blockIdx.x * 256 + threadIdx.x;
    if (v >= NN) return;
    int s = rowptr[v], e = rowptr[v + 1];
    float d = 0.f;
    for (int i = s; i < e; ++i) d += __int_as_float(epair[i].y);
    dis[v] = (d > 0.f) ? (1.0f / sqrtf(d)) : 0.f;
}

__global__ void norm_k(const int* __restrict__ rowptr, const float* __restrict__ dis,
                       int2* __restrict__ epair) {
    int v = blockIdx.x * 256 + threadIdx.x;
    if (v >= NN) return;
    float dv = dis[v];
    int s = rowptr[v], e = rowptr[v + 1];
    int* ey = (int*)epair;
    for (int i = s; i < e; ++i) {
        int2 p = epair[i];
        float w = dis[p.x] * __int_as_float(p.y) * dv;
        ey[2 * i + 1] = __float_as_int(w);
    }
}

// ---------------------------------------------------------------------------
// Weight prep: Wt[j][k] = bf16(W[k][j]);  W is [K][128] fp32, Wt is [128][K]
// ---------------------------------------------------------------------------
template <int K>
__global__ void wt_k(const float* __restrict__ W, u16* __restrict__ Wt) {
    int id = blockIdx.x * 256 + threadIdx.x;   // grid = 128*K/256
    int j = id / K, k = id % K;
    Wt[(size_t)j * K + k] = f2bf(W[(size_t)k * 128 + j]);
}

// ---------------------------------------------------------------------------
// Propagation
// ---------------------------------------------------------------------------

// 16-wide fp32 features (layer-0 hops): 4 lanes per node, float4 each.
// Unroll x4 for memory-level parallelism.
__global__ void prop16_k(const float* __restrict__ hin, float* __restrict__ hout,
                         const int* __restrict__ rowptr, const int2* __restrict__ epair) {
    int t = blockIdx.x * 256 + threadIdx.x;
    int v = t >> 2, q = t & 3;
    if (v >= NN) return;
    int s = rowptr[v], e = rowptr[v + 1];
    const float* __restrict__ hq = hin + q * 4;
    float4 a0 = make_float4(0.f, 0.f, 0.f, 0.f);
    float4 a1 = make_float4(0.f, 0.f, 0.f, 0.f);
    int i = s;
    for (; i + 3 < e; i += 4) {
        int2 p0 = epair[i];
        int2 p1 = epair[i + 1];
        int2 p2 = epair[i + 2];
        int2 p3 = epair[i + 3];
        float4 h0 = *reinterpret_cast<const float4*>(hq + (size_t)p0.x * 16);
        float4 h1 = *reinterpret_cast<const float4*>(hq + (size_t)p1.x * 16);
        float4 h2 = *reinterpret_cast<const float4*>(hq + (size_t)p2.x * 16);
        float4 h3 = *reinterpret_cast<const float4*>(hq + (size_t)p3.x * 16);
        float w0 = __int_as_float(p0.y), w1 = __int_as_float(p1.y);
        float w2 = __int_as_float(p2.y), w3 = __int_as_float(p3.y);
        a0.x += w0 * h0.x; a0.y += w0 * h0.y; a0.z += w0 * h0.z; a0.w += w0 * h0.w;
        a1.x += w1 * h1.x; a1.y += w1 * h1.y; a1.z += w1 * h1.z; a1.w += w1 * h1.w;
        a0.x += w2 * h2.x; a0.y += w2 * h2.y; a0.z += w2 * h2.z; a0.w += w2 * h2.w;
        a1.x += w3 * h3.x; a1.y += w3 * h3.y; a1.z += w3 * h3.z; a1.w += w3 * h3.w;
    }
    for (; i < e; ++i) {
        int2 p = epair[i];
        float w = __int_as_float(p.y);
        float4 h = *reinterpret_cast<const float4*>(hq + (size_t)p.x * 16);
        a0.x += w * h.x; a0.y += w * h.y; a0.z += w * h.z; a0.w += w * h.w;
    }
    float4 acc = make_float4(a0.x + a1.x, a0.y + a1.y, a0.z + a1.z, a0.w + a1.w);
    *reinterpret_cast<float4*>(hout + (size_t)v * 16 + q * 4) = acc;
}

// Pack x,P1,P2,P3 (fp32 [NN][16] each) -> Xcat bf16 [NN][64]
__global__ void pack_k(const float* __restrict__ x, const float* __restrict__ p1,
                       const float* __restrict__ p2, const float* __restrict__ p3,
                       u16* __restrict__ Xcat) {
    int id = blockIdx.x * 256 + threadIdx.x;
    if (id >= NN * 4) return;
    int v = id >> 2, s = id & 3;
    const float* src = (s == 0 ? x : s == 1 ? p1 : s == 2 ? p2 : p3) + (size_t)v * 16;
    unsigned* dst = (unsigned*)(Xcat + (size_t)v * 64 + s * 16);
#pragma unroll
    for (int f = 0; f < 8; ++f) {
        dst[f] = (unsigned)f2bf(src[2 * f]) | ((unsigned)f2bf(src[2 * f + 1]) << 16);
    }
}

// 128-wide bf16 features in a stride-512 concat buffer: ONE wave per node.
// Unroll x4: 4 independent 256B gathers in flight per wave (latency hiding).
__global__ __launch_bounds__(256) void propbf_k(
    const u16* __restrict__ hin, u16* __restrict__ hout,
    const int* __restrict__ rowptr, const int2* __restrict__ epair) {
    int wid = (blockIdx.x * 256 + threadIdx.x) >> 6;   // grid = NN*64/256
    int lane = threadIdx.x & 63;
    int v = __builtin_amdgcn_readfirstlane(wid);
    int s = rowptr[v], e = rowptr[v + 1];
    const u16* __restrict__ hb = hin + lane * 2;
    float ax0 = 0.f, ay0 = 0.f, ax1 = 0.f, ay1 = 0.f;
    float ax2 = 0.f, ay2 = 0.f, ax3 = 0.f, ay3 = 0.f;
    int i = s;
    for (; i + 3 < e; i += 4) {
        int2 p0 = epair[i];
        int2 p1 = epair[i + 1];
        int2 p2 = epair[i + 2];
        int2 p3 = epair[i + 3];
        unsigned u0 = *(const unsigned*)(hb + (size_t)p0.x * 512);
        unsigned u1 = *(const unsigned*)(hb + (size_t)p1.x * 512);
        unsigned u2 = *(const unsigned*)(hb + (size_t)p2.x * 512);
        unsigned u3 = *(const unsigned*)(hb + (size_t)p3.x * 512);
        float w0 = __int_as_float(p0.y), w1 = __int_as_float(p1.y);
        float w2 = __int_as_float(p2.y), w3 = __int_as_float(p3.y);
        ax0 += w0 * bflo(u0); ay0 += w0 * bfhi(u0);
        ax1 += w1 * bflo(u1); ay1 += w1 * bfhi(u1);
        ax2 += w2 * bflo(u2); ay2 += w2 * bfhi(u2);
        ax3 += w3 * bflo(u3); ay3 += w3 * bfhi(u3);
    }
    for (; i < e; ++i) {
        int2 p0 = epair[i];
        unsigned u0 = *(const unsigned*)(hb + (size_t)p0.x * 512);
        float w0 = __int_as_float(p0.y);
        ax0 += w0 * bflo(u0); ay0 += w0 * bfhi(u0);
    }
    float rx = (ax0 + ax1) + (ax2 + ax3);
    float ry = (ay0 + ay1) + (ay2 + ay3);
    unsigned o = (unsigned)f2bf(rx) | ((unsigned)f2bf(ry) << 16);
    *(unsigned*)(hout + (size_t)v * 512 + lane * 2) = o;
}

// ---------------------------------------------------------------------------
// MFMA GEMM v2: C[NN][128] = A[NN][K]bf16 @ W[K][128] (+bias, relu) -> bf16
// out stride 512 (slice 0 of concat buffer). LDS-staged swizzled Bt,
// persistent 8-wave blocks with atomic ticket (deterministic: tiles pure).
// ---------------------------------------------------------------------------
template <int KSTEPS, int RELU>
__global__ __launch_bounds__(512, 2) void mgemm2_k(
    const u16* __restrict__ A, const u16* __restrict__ Bt,
    const float* __restrict__ bias, u16* __restrict__ outb,
    int* __restrict__ ctr, int ntiles) {
    const int K = KSTEPS * 32;
    const int BBYTES = 128 * K * 2;
    __shared__ u16 smB[128 * KSTEPS * 32];
    __shared__ int smt;
    int tid = threadIdx.x;

    // Stage B: LDS[d] = Bt[d ^ swz(row(d))]; read side applies same XOR.
    for (int d = tid * 16; d < BBYTES; d += 512 * 16) {
        int rowb = d / (K * 2);
        int src = d ^ ((rowb & 7) << 4);
        *(short8*)((char*)smB + d) = *(const short8*)((const char*)Bt + src);
    }

    int lane = tid & 63;
    int wv = tid >> 6;
    int r = lane & 15, h = lane >> 4;
    float bj[8];
#pragma unroll
    for (int j = 0; j < 8; ++j) bj[j] = bias[j * 16 + r];
    const char* bbase = (const char*)smB;

    for (;;) {
        __syncthreads();                      // covers staging + smt reuse
        if (tid == 0) smt = atomicAdd(ctr, 1);
        __syncthreads();
        int t = smt;
        if (t >= ntiles) break;               // uniform across block
        int v0 = t * 256 + wv * 32;
        if (v0 >= NN) continue;               // converges at loop-top barrier

        const u16* a0p = A + (size_t)(v0 + r) * K + h * 8;
        const u16* a1p = a0p + (size_t)16 * K;
        f32x4 acc0[8], acc1[8];
#pragma unroll
        for (int j = 0; j < 8; ++j) {
            acc0[j] = {0.f, 0.f, 0.f, 0.f};
            acc1[j] = {0.f, 0.f, 0.f, 0.f};
        }
#pragma unroll
        for (int kk = 0; kk < KSTEPS; ++kk) {
            short8 a0 = *(const short8*)(a0p + kk * 32);
            short8 a1 = *(const short8*)(a1p + kk * 32);
#pragma unroll
            for (int j = 0; j < 8; ++j) {
                int bb = ((j * 16 + r) * K * 2 + kk * 64 + h * 16) ^ ((r & 7) << 4);
                short8 b = *(const short8*)(bbase + bb);
                acc0[j] = __builtin_amdgcn_mfma_f32_16x16x32_bf16(a0, b, acc0[j], 0, 0, 0);
                acc1[j] = __builtin_amdgcn_mfma_f32_16x16x32_bf16(a1, b, acc1[j], 0, 0, 0);
            }
        }
        // Epilogue: i-outer, j-inner so 32B half-line stores are adjacent.
#pragma unroll
        for (int i = 0; i < 4; ++i) {
            int row0 = v0 + h * 4 + i;
#pragma unroll
            for (int j = 0; j < 8; ++j) {
                float c0 = acc0[j][i] + bj[j];
                float c1 = acc1[j][i] + bj[j];
                if (RELU) { c0 = fmaxf(c0, 0.f); c1 = fmaxf(c1, 0.f); }
                outb[(size_t)row0 * 512 + j * 16 + r] = f2bf(c0);
                outb[(size_t)(row0 + 16) * 512 + j * 16 + r] = f2bf(c1);
            }
        }
    }
}

// Final fc: out[v][0..3] = bfc + h[v][:] @ Wfc[128][4]; h bf16 stride 512.
__global__ void fcb_k(const u16* __restrict__ H, const float* __restrict__ Wfc,
                      const float* __restrict__ bfc, float* __restrict__ out) {
    int t = blockIdx.x * 256 + threadIdx.x;   // grid = NN*64/256
    int v = t >> 6, p = t & 63;
    unsigned u = *(const unsigned*)(H + (size_t)v * 512 + p * 2);
    float h0 = bflo(u), h1 = bfhi(u);
    float4 w0 = reinterpret_cast<const float4*>(Wfc)[2 * p];
    float4 w1 = reinterpret_cast<const float4*>(Wfc)[2 * p + 1];
    float s0 = h0 * w0.x + h1 * w1.x;
    float s1 = h0 * w0.y + h1 * w1.y;
    float s2 = h0 * w0.z + h1 * w1.z;
    float s3 = h0 * w0.w + h1 * w1.w;
#pragma unroll
    for (int off = 32; off; off >>= 1) {
        s0 += __shfl_xor(s0, off);
        s1 += __shfl_xor(s1, off);
        s2 += __shfl_xor(s2, off);
        s3 += __shfl_xor(s3, off);
    }
    if (p == 0) {
        float4 o = make_float4(s0 + bfc[0], s1 + bfc[1], s2 + bfc[2], s3 + bfc[3]);
        reinterpret_cast<float4*>(out)[v] = o;
    }
}

// ---------------------------------------------------------------------------

extern "C" void kernel_launch(void* const* d_in, const int* in_sizes, int n_in,
                              void* d_out, int out_size, void* d_ws, size_t ws_size,
                              hipStream_t stream) {
    const float* x    = (const float*)d_in[0];
    const int*   ei   = (const int*)d_in[1];      // [2][E] int32
    const float* ea   = (const float*)d_in[2];    // [E]
    const float* W0   = (const float*)d_in[3];    // [4][16][128] = [64][128]
    const float* b0   = (const float*)d_in[4];
    const float* W1   = (const float*)d_in[5];    // [4][128][128] = [512][128]
    const float* b1   = (const float*)d_in[6];
    const float* W2   = (const float*)d_in[7];
    const float* b2   = (const float*)d_in[8];
    const float* Wfc  = (const float*)d_in[9];    // [128][4]
    const float* bfc  = (const float*)d_in[10];
    float* out = (float*)d_out;

    const int* row = ei;
    const int* col = ei + NE;

    // ws layout (256B aligned chunks)
    char* w = (char*)d_ws;
    size_t off = 0;
    auto alloc = [&](size_t bytes) {
        size_t o = off;
        off += (bytes + 255) & ~(size_t)255;
        return (void*)(w + o);
    };
    int*   cnt    = (int*)  alloc((size_t)NN * 4);       // first (memset)
    int*   ctr    = (int*)  alloc(3 * 4);                // gemm tickets
    size_t zero_bytes = off;
    int*   rowptr = (int*)  alloc((size_t)(NN + 1) * 4);
    int*   blksum = (int*)  alloc(512 * 4);
    float* dis    = (float*)alloc((size_t)NN * 4);
    int2*  epair  = (int2*) alloc((size_t)NE * 8);
    u16*   Wt0    = (u16*)  alloc((size_t)128 * 64 * 2);
    u16*   Wt1    = (u16*)  alloc((size_t)128 * 512 * 2);
    u16*   Wt2    = (u16*)  alloc((size_t)128 * 512 * 2);
    // union region: P1,P2,P3,Xcat live early only
    char*  ureg   = (char*) alloc((size_t)NN * 128 * 4); // 51.2 MB
    float* P1   = (float*)(ureg);
    float* P2   = (float*)(ureg + (size_t)NN * 16 * 4);
    float* P3   = (float*)(ureg + (size_t)NN * 32 * 4);
    u16*   Xcat = (u16*)  (ureg + (size_t)NN * 48 * 4);
    u16*   Hcat = (u16*)  alloc((size_t)NN * 512 * 2);   // 102.4 MB
    int*   rank = (int*)Hcat;   // alias: dead before Hcat first written
    (void)ws_size;

    const int nScanB = (NN + 255) / 256;  // 391
    const int nEdgeB = NE / 256;          // 6250
    const int nPropB = NN * 64 / 256;     // 25000 (one wave per node)
    const int nTiles = (NN + 255) / 256;  // 391 row-tiles of 256

    hipMemsetAsync(cnt, 0, zero_bytes, stream);
    count_k<<<nEdgeB, 256, 0, stream>>>(col, cnt, rank);
    scan1_k<<<nScanB, 256, 0, stream>>>(cnt, rowptr, blksum);
    scan2_k<<<1, 512, 0, stream>>>(blksum, nScanB);
    scan3_k<<<nScanB, 256, 0, stream>>>(rowptr, blksum);
    scatter_k<<<nEdgeB, 256, 0, stream>>>(row, col, ea, rowptr, rank, epair);
    dis_k<<<nScanB, 256, 0, stream>>>(rowptr, epair, dis);
    norm_k<<<nScanB, 256, 0, stream>>>(rowptr, dis, epair);

    // Weight transposes (bf16)
    wt_k<64> <<<32,  256, 0, stream>>>(W0, Wt0);
    wt_k<512><<<256, 256, 0, stream>>>(W1, Wt1);
    wt_k<512><<<256, 256, 0, stream>>>(W2, Wt2);

    // Layer 0: fp32 16-wide hops, pack to bf16, MFMA K=64 -> Hcat slice0
    const int n16B = (NN * 4 + 255) / 256;
    prop16_k<<<n16B, 256, 0, stream>>>(x,  P1, rowptr, epair);
    prop16_k<<<n16B, 256, 0, stream>>>(P1, P2, rowptr, epair);
    prop16_k<<<n16B, 256, 0, stream>>>(P2, P3, rowptr, epair);
    pack_k<<<n16B, 256, 0, stream>>>(x, P1, P2, P3, Xcat);
    mgemm2_k<2, 1><<<256, 512, 0, stream>>>(Xcat, Wt0, b0, Hcat, ctr + 0, nTiles);

    // Layer 1: hops fill slices 1..3, fused GEMM K=512 -> slice0 (in place)
    propbf_k<<<nPropB, 256, 0, stream>>>(Hcat,       Hcat + 128, rowptr, epair);
    propbf_k<<<nPropB, 256, 0, stream>>>(Hcat + 128, Hcat + 256, rowptr, epair);
    propbf_k<<<nPropB, 256, 0, stream>>>(Hcat + 256, Hcat + 384, rowptr, epair);
    mgemm2_k<16, 1><<<256, 512, 0, stream>>>(Hcat, Wt1, b1, Hcat, ctr + 1, nTiles);

    // Layer 2: same, final GEMM -> slice0 bf16 (no relu)
    propbf_k<<<nPropB, 256, 0, stream>>>(Hcat,       Hcat + 128, rowptr, epair);
    propbf_k<<<nPropB, 256, 0, stream>>>(Hcat + 128, Hcat + 256, rowptr, epair);
    propbf_k<<<nPropB, 256, 0, stream>>>(Hcat + 256, Hcat + 384, rowptr, epair);
    mgemm2_k<16, 0><<<256, 512, 0, stream>>>(Hcat, Wt2, b2, Hcat, ctr + 2, nTiles);

    // Final projection (reads bf16 slice0)
    fcb_k<<<nPropB, 256, 0, stream>>>(Hcat, Wfc, bfc, out);
}

// Round 6
// 681.025 us; speedup vs baseline: 2.8065x; 1.0017x over previous
//
#include <hip/hip_runtime.h>
#include <cstddef>
#include <cstdint>

// Problem constants (from reference)
#define NN 100000
#define NE 1600000
// F_IN=16, HID=128, OUT=4, K=3

typedef unsigned short u16;
using short8 = __attribute__((ext_vector_type(8))) short;  // 8 bf16 (4 VGPRs)
using f32x4  = __attribute__((ext_vector_type(4))) float;  // MFMA accum

// bf16 helpers (round-to-nearest-even via bit trick)
__device__ inline u16 f2bf(float f) {
    unsigned u = __float_as_uint(f);
    unsigned r = u + 0x7fffu + ((u >> 16) & 1u);
    return (u16)(r >> 16);
}
__device__ inline float bflo(unsigned u) { return __uint_as_float(u << 16); }
__device__ inline float bfhi(unsigned u) { return __uint_as_float(u & 0xffff0000u); }

// ---------------------------------------------------------------------------
// Graph preprocessing (atomic-light CSR build)
// ---------------------------------------------------------------------------

__global__ void count_k(const int* __restrict__ col, int* __restrict__ cnt,
                        int* __restrict__ rank) {
    int e = blockIdx.x * 256 + threadIdx.x;   // grid exactly NE/256
    int c = col[e];
    rank[e] = atomicAdd(&cnt[c], 1);
}

__global__ void scan1_k(const int* __restrict__ cnt, int* __restrict__ exc,
                        int* __restrict__ blksum) {
    __shared__ int sm[256];
    int i = blockIdx.x * 256 + threadIdx.x;
    int v = (i < NN) ? cnt[i] : 0;
    sm[threadIdx.x] = v;
    __syncthreads();
    for (int off = 1; off < 256; off <<= 1) {
        int t = (threadIdx.x >= off) ? sm[threadIdx.x - off] : 0;
        __syncthreads();
        sm[threadIdx.x] += t;
        __syncthreads();
    }
    if (i < NN) exc[i] = sm[threadIdx.x] - v;
    if (threadIdx.x == 255) blksum[blockIdx.x] = sm[255];
}

__global__ void scan2_k(int* __restrict__ blksum, int nb) {
    __shared__ int sm[512];
    int t = threadIdx.x;
    int v = (t < nb) ? blksum[t] : 0;
    sm[t] = v;
    __syncthreads();
    for (int off = 1; off < 512; off <<= 1) {
        int x = (t >= off) ? sm[t - off] : 0;
        __syncthreads();
        sm[t] += x;
        __syncthreads();
    }
    if (t < nb) blksum[t] = sm[t] - v;
}

__global__ void scan3_k(int* __restrict__ rowptr, const int* __restrict__ blksum) {
    int i = blockIdx.x * 256 + threadIdx.x;
    if (i < NN) rowptr[i] += blksum[blockIdx.x];
    if (i == 0) rowptr[NN] = NE;
}

__global__ void scatter_k(const int* __restrict__ row, const int* __restrict__ col,
                          const float* __restrict__ ew, const int* __restrict__ rowptr,
                          const int* __restrict__ rank, int2* __restrict__ epair) {
    int e = blockIdx.x * 256 + threadIdx.x;
    int c = col[e];
    int p = rowptr[c] + rank[e];
    int2 pr;
    pr.x = row[e];
    pr.y = __float_as_int(ew[e]);
    epair[p] = pr;
}

__global__ void dis_k(const int* __restrict__ rowptr, const int2* __restrict__ epair,
                      float* __restrict__ dis) {
    int v = blockIdx.x * 256 + threadIdx.x;
    if (v >= NN) return;
    int s = rowptr[v], e = rowptr[v + 1];
    float d = 0.f;
    for (int i = s; i < e; ++i) d += __int_as_float(epair[i].y);
    dis[v] = (d > 0.f) ? (1.0f / sqrtf(d)) : 0.f;
}

__global__ void norm_k(const int* __restrict__ rowptr, const float* __restrict__ dis,
                       int2* __restrict__ epair) {
    int v = blockIdx.x * 256 + threadIdx.x;
    if (v >= NN) return;
    float dv = dis[v];
    int s = rowptr[v], e = rowptr[v + 1];
    int* ey = (int*)epair;
    for (int i = s; i < e; ++i) {
        int2 p = epair[i];
        float w = dis[p.x] * __int_as_float(p.y) * dv;
        ey[2 * i + 1] = __float_as_int(w);
    }
}

// ---------------------------------------------------------------------------
// Weight prep: Wt[j][k] = bf16(W[k][j]);  W is [K][128] fp32, Wt is [128][K]
// ---------------------------------------------------------------------------
template <int K>
__global__ void wt_k(const float* __restrict__ W, u16* __restrict__ Wt) {
    int id = blockIdx.x * 256 + threadIdx.x;   // grid = 128*K/256
    int j = id / K, k = id % K;
    Wt[(size_t)j * K + k] = f2bf(W[(size_t)k * 128 + j]);
}

// ---------------------------------------------------------------------------
// Propagation
// ---------------------------------------------------------------------------

// 16-wide fp32 features (layer-0 hops): 4 lanes per node, float4 each.
__global__ void prop16_k(const float* __restrict__ hin, float* __restrict__ hout,
                         const int* __restrict__ rowptr, const int2* __restrict__ epair) {
    int t = blockIdx.x * 256 + threadIdx.x;
    int v = t >> 2, q = t & 3;
    if (v >= NN) return;
    int s = rowptr[v], e = rowptr[v + 1];
    const float* __restrict__ hq = hin + q * 4;
    float4 a0 = make_float4(0.f, 0.f, 0.f, 0.f);
    float4 a1 = make_float4(0.f, 0.f, 0.f, 0.f);
    int i = s;
    for (; i + 3 < e; i += 4) {
        int2 p0 = epair[i];
        int2 p1 = epair[i + 1];
        int2 p2 = epair[i + 2];
        int2 p3 = epair[i + 3];
        float4 h0 = *reinterpret_cast<const float4*>(hq + (size_t)p0.x * 16);
        float4 h1 = *reinterpret_cast<const float4*>(hq + (size_t)p1.x * 16);
        float4 h2 = *reinterpret_cast<const float4*>(hq + (size_t)p2.x * 16);
        float4 h3 = *reinterpret_cast<const float4*>(hq + (size_t)p3.x * 16);
        float w0 = __int_as_float(p0.y), w1 = __int_as_float(p1.y);
        float w2 = __int_as_float(p2.y), w3 = __int_as_float(p3.y);
        a0.x += w0 * h0.x; a0.y += w0 * h0.y; a0.z += w0 * h0.z; a0.w += w0 * h0.w;
        a1.x += w1 * h1.x; a1.y += w1 * h1.y; a1.z += w1 * h1.z; a1.w += w1 * h1.w;
        a0.x += w2 * h2.x; a0.y += w2 * h2.y; a0.z += w2 * h2.z; a0.w += w2 * h2.w;
        a1.x += w3 * h3.x; a1.y += w3 * h3.y; a1.z += w3 * h3.z; a1.w += w3 * h3.w;
    }
    for (; i < e; ++i) {
        int2 p = epair[i];
        float w = __int_as_float(p.y);
        float4 h = *reinterpret_cast<const float4*>(hq + (size_t)p.x * 16);
        a0.x += w * h.x; a0.y += w * h.y; a0.z += w * h.z; a0.w += w * h.w;
    }
    float4 acc = make_float4(a0.x + a1.x, a0.y + a1.y, a0.z + a1.z, a0.w + a1.w);
    *reinterpret_cast<float4*>(hout + (size_t)v * 16 + q * 4) = acc;
}

// Pack x,P1,P2,P3 (fp32 [NN][16] each) -> Xcat bf16 [NN][64]
__global__ void pack_k(const float* __restrict__ x, const float* __restrict__ p1,
                       const float* __restrict__ p2, const float* __restrict__ p3,
                       u16* __restrict__ Xcat) {
    int id = blockIdx.x * 256 + threadIdx.x;
    if (id >= NN * 4) return;
    int v = id >> 2, s = id & 3;
    const float* src = (s == 0 ? x : s == 1 ? p1 : s == 2 ? p2 : p3) + (size_t)v * 16;
    unsigned* dst = (unsigned*)(Xcat + (size_t)v * 64 + s * 16);
#pragma unroll
    for (int f = 0; f < 8; ++f) {
        dst[f] = (unsigned)f2bf(src[2 * f]) | ((unsigned)f2bf(src[2 * f + 1]) << 16);
    }
}

// 128-wide bf16 prop v2: ONE wave per node; 16 lanes serve one edge with
// dwordx4 (16B = 8 features per lane) -> 4 edges per wave-load, unroll x2
// (8 edges / 2KB in flight). Tail edges masked with (src=0, w=0) -> exact 0.
// Epilogue: 2-step shfl_xor(16,32) folds the 4 groups; group 0 stores 256B.
__global__ __launch_bounds__(256) void propbf_k(
    const u16* __restrict__ hin, u16* __restrict__ hout,
    const int* __restrict__ rowptr, const int2* __restrict__ epair) {
    int wid = (blockIdx.x * 256 + threadIdx.x) >> 6;   // grid = NN*64/256
    int lane = threadIdx.x & 63;
    int g = lane >> 4;          // edge group 0..3
    int l = lane & 15;          // feature slot: features [8l, 8l+8)
    int v = __builtin_amdgcn_readfirstlane(wid);
    int s = rowptr[v], e = rowptr[v + 1];
    const u16* __restrict__ hb = hin + l * 8;
    float a[8];
#pragma unroll
    for (int k = 0; k < 8; ++k) a[k] = 0.f;

    int i = s;
    for (; i + 7 < e; i += 8) {
        int2 pa = epair[i + g];
        int2 pb = epair[i + 4 + g];
        uint4 ha = *(const uint4*)(hb + (size_t)pa.x * 512);
        uint4 hc = *(const uint4*)(hb + (size_t)pb.x * 512);
        float wa = __int_as_float(pa.y), wb = __int_as_float(pb.y);
        a[0] += wa * bflo(ha.x); a[1] += wa * bfhi(ha.x);
        a[2] += wa * bflo(ha.y); a[3] += wa * bfhi(ha.y);
        a[4] += wa * bflo(ha.z); a[5] += wa * bfhi(ha.z);
        a[6] += wa * bflo(ha.w); a[7] += wa * bfhi(ha.w);
        a[0] += wb * bflo(hc.x); a[1] += wb * bfhi(hc.x);
        a[2] += wb * bflo(hc.y); a[3] += wb * bfhi(hc.y);
        a[4] += wb * bflo(hc.z); a[5] += wb * bfhi(hc.z);
        a[6] += wb * bflo(hc.w); a[7] += wb * bfhi(hc.w);
    }
    for (; i < e; i += 4) {
        int idx = i + g;
        int2 p = (idx < e) ? epair[idx] : make_int2(0, 0);
        uint4 h = *(const uint4*)(hb + (size_t)p.x * 512);
        float w = __int_as_float(p.y);
        a[0] += w * bflo(h.x); a[1] += w * bfhi(h.x);
        a[2] += w * bflo(h.y); a[3] += w * bfhi(h.y);
        a[4] += w * bflo(h.z); a[5] += w * bfhi(h.z);
        a[6] += w * bflo(h.w); a[7] += w * bfhi(h.w);
    }
    // fold the 4 edge-groups (lanes l, l+16, l+32, l+48)
#pragma unroll
    for (int k = 0; k < 8; ++k) {
        a[k] += __shfl_xor(a[k], 16);
        a[k] += __shfl_xor(a[k], 32);
    }
    if (g == 0) {
        uint4 o;
        o.x = (unsigned)f2bf(a[0]) | ((unsigned)f2bf(a[1]) << 16);
        o.y = (unsigned)f2bf(a[2]) | ((unsigned)f2bf(a[3]) << 16);
        o.z = (unsigned)f2bf(a[4]) | ((unsigned)f2bf(a[5]) << 16);
        o.w = (unsigned)f2bf(a[6]) | ((unsigned)f2bf(a[7]) << 16);
        *(uint4*)(hout + (size_t)v * 512 + l * 8) = o;
    }
}

// ---------------------------------------------------------------------------
// MFMA GEMM v2: C[NN][128] = A[NN][K]bf16 @ W[K][128] (+bias, relu) -> bf16
// out stride 512 (slice 0 of concat buffer). LDS-staged swizzled Bt,
// persistent 8-wave blocks with atomic ticket (deterministic: tiles pure).
// ---------------------------------------------------------------------------
template <int KSTEPS, int RELU>
__global__ __launch_bounds__(512, 2) void mgemm2_k(
    const u16* __restrict__ A, const u16* __restrict__ Bt,
    const float* __restrict__ bias, u16* __restrict__ outb,
    int* __restrict__ ctr, int ntiles) {
    const int K = KSTEPS * 32;
    const int BBYTES = 128 * K * 2;
    __shared__ u16 smB[128 * KSTEPS * 32];
    __shared__ int smt;
    int tid = threadIdx.x;

    // Stage B: LDS[d] = Bt[d ^ swz(row(d))]; read side applies same XOR.
    for (int d = tid * 16; d < BBYTES; d += 512 * 16) {
        int rowb = d / (K * 2);
        int src = d ^ ((rowb & 7) << 4);
        *(short8*)((char*)smB + d) = *(const short8*)((const char*)Bt + src);
    }

    int lane = tid & 63;
    int wv = tid >> 6;
    int r = lane & 15, h = lane >> 4;
    float bj[8];
#pragma unroll
    for (int j = 0; j < 8; ++j) bj[j] = bias[j * 16 + r];
    const char* bbase = (const char*)smB;

    for (;;) {
        __syncthreads();                      // covers staging + smt reuse
        if (tid == 0) smt = atomicAdd(ctr, 1);
        __syncthreads();
        int t = smt;
        if (t >= ntiles) break;               // uniform across block
        int v0 = t * 256 + wv * 32;
        if (v0 >= NN) continue;               // converges at loop-top barrier

        const u16* a0p = A + (size_t)(v0 + r) * K + h * 8;
        const u16* a1p = a0p + (size_t)16 * K;
        f32x4 acc0[8], acc1[8];
#pragma unroll
        for (int j = 0; j < 8; ++j) {
            acc0[j] = {0.f, 0.f, 0.f, 0.f};
            acc1[j] = {0.f, 0.f, 0.f, 0.f};
        }
#pragma unroll
        for (int kk = 0; kk < KSTEPS; ++kk) {
            short8 a0 = *(const short8*)(a0p + kk * 32);
            short8 a1 = *(const short8*)(a1p + kk * 32);
#pragma unroll
            for (int j = 0; j < 8; ++j) {
                int bb = ((j * 16 + r) * K * 2 + kk * 64 + h * 16) ^ ((r & 7) << 4);
                short8 b = *(const short8*)(bbase + bb);
                acc0[j] = __builtin_amdgcn_mfma_f32_16x16x32_bf16(a0, b, acc0[j], 0, 0, 0);
                acc1[j] = __builtin_amdgcn_mfma_f32_16x16x32_bf16(a1, b, acc1[j], 0, 0, 0);
            }
        }
        // Epilogue: i-outer, j-inner so 32B half-line stores are adjacent.
#pragma unroll
        for (int i = 0; i < 4; ++i) {
            int row0 = v0 + h * 4 + i;
#pragma unroll
            for (int j = 0; j < 8; ++j) {
                float c0 = acc0[j][i] + bj[j];
                float c1 = acc1[j][i] + bj[j];
                if (RELU) { c0 = fmaxf(c0, 0.f); c1 = fmaxf(c1, 0.f); }
                outb[(size_t)row0 * 512 + j * 16 + r] = f2bf(c0);
                outb[(size_t)(row0 + 16) * 512 + j * 16 + r] = f2bf(c1);
            }
        }
    }
}

// Final fc: out[v][0..3] = bfc + h[v][:] @ Wfc[128][4]; h bf16 stride 512.
__global__ void fcb_k(const u16* __restrict__ H, const float* __restrict__ Wfc,
                      const float* __restrict__ bfc, float* __restrict__ out) {
    int t = blockIdx.x * 256 + threadIdx.x;   // grid = NN*64/256
    int v = t >> 6, p = t & 63;
    unsigned u = *(const unsigned*)(H + (size_t)v * 512 + p * 2);
    float h0 = bflo(u), h1 = bfhi(u);
    float4 w0 = reinterpret_cast<const float4*>(Wfc)[2 * p];
    float4 w1 = reinterpret_cast<const float4*>(Wfc)[2 * p + 1];
    float s0 = h0 * w0.x + h1 * w1.x;
    float s1 = h0 * w0.y + h1 * w1.y;
    float s2 = h0 * w0.z + h1 * w1.z;
    float s3 = h0 * w0.w + h1 * w1.w;
#pragma unroll
    for (int off = 32; off; off >>= 1) {
        s0 += __shfl_xor(s0, off);
        s1 += __shfl_xor(s1, off);
        s2 += __shfl_xor(s2, off);
        s3 += __shfl_xor(s3, off);
    }
    if (p == 0) {
        float4 o = make_float4(s0 + bfc[0], s1 + bfc[1], s2 + bfc[2], s3 + bfc[3]);
        reinterpret_cast<float4*>(out)[v] = o;
    }
}

// ---------------------------------------------------------------------------

extern "C" void kernel_launch(void* const* d_in, const int* in_sizes, int n_in,
                              void* d_out, int out_size, void* d_ws, size_t ws_size,
                              hipStream_t stream) {
    const float* x    = (const float*)d_in[0];
    const int*   ei   = (const int*)d_in[1];      // [2][E] int32
    const float* ea   = (const float*)d_in[2];    // [E]
    const float* W0   = (const float*)d_in[3];    // [4][16][128] = [64][128]
    const float* b0   = (const float*)d_in[4];
    const float* W1   = (const float*)d_in[5];    // [4][128][128] = [512][128]
    const float* b1   = (const float*)d_in[6];
    const float* W2   = (const float*)d_in[7];
    const float* b2   = (const float*)d_in[8];
    const float* Wfc  = (const float*)d_in[9];    // [128][4]
    const float* bfc  = (const float*)d_in[10];
    float* out = (float*)d_out;

    const int* row = ei;
    const int* col = ei + NE;

    // ws layout (256B aligned chunks)
    char* w = (char*)d_ws;
    size_t off = 0;
    auto alloc = [&](size_t bytes) {
        size_t o = off;
        off += (bytes + 255) & ~(size_t)255;
        return (void*)(w + o);
    };
    int*   cnt    = (int*)  alloc((size_t)NN * 4);       // first (memset)
    int*   ctr    = (int*)  alloc(3 * 4);                // gemm tickets
    size_t zero_bytes = off;
    int*   rowptr = (int*)  alloc((size_t)(NN + 1) * 4);
    int*   blksum = (int*)  alloc(512 * 4);
    float* dis    = (float*)alloc((size_t)NN * 4);
    int2*  epair  = (int2*) alloc((size_t)NE * 8);
    u16*   Wt0    = (u16*)  alloc((size_t)128 * 64 * 2);
    u16*   Wt1    = (u16*)  alloc((size_t)128 * 512 * 2);
    u16*   Wt2    = (u16*)  alloc((size_t)128 * 512 * 2);
    // union region: P1,P2,P3,Xcat live early only
    char*  ureg   = (char*) alloc((size_t)NN * 128 * 4); // 51.2 MB
    float* P1   = (float*)(ureg);
    float* P2   = (float*)(ureg + (size_t)NN * 16 * 4);
    float* P3   = (float*)(ureg + (size_t)NN * 32 * 4);
    u16*   Xcat = (u16*)  (ureg + (size_t)NN * 48 * 4);
    u16*   Hcat = (u16*)  alloc((size_t)NN * 512 * 2);   // 102.4 MB
    int*   rank = (int*)Hcat;   // alias: dead before Hcat first written
    (void)ws_size;

    const int nScanB = (NN + 255) / 256;  // 391
    const int nEdgeB = NE / 256;          // 6250
    const int nPropB = NN * 64 / 256;     // 25000 (one wave per node)
    const int nTiles = (NN + 255) / 256;  // 391 row-tiles of 256

    hipMemsetAsync(cnt, 0, zero_bytes, stream);
    count_k<<<nEdgeB, 256, 0, stream>>>(col, cnt, rank);
    scan1_k<<<nScanB, 256, 0, stream>>>(cnt, rowptr, blksum);
    scan2_k<<<1, 512, 0, stream>>>(blksum, nScanB);
    scan3_k<<<nScanB, 256, 0, stream>>>(rowptr, blksum);
    scatter_k<<<nEdgeB, 256, 0, stream>>>(row, col, ea, rowptr, rank, epair);
    dis_k<<<nScanB, 256, 0, stream>>>(rowptr, epair, dis);
    norm_k<<<nScanB, 256, 0, stream>>>(rowptr, dis, epair);

    // Weight transposes (bf16)
    wt_k<64> <<<32,  256, 0, stream>>>(W0, Wt0);
    wt_k<512><<<256, 256, 0, stream>>>(W1, Wt1);
    wt_k<512><<<256, 256, 0, stream>>>(W2, Wt2);

    // Layer 0: fp32 16-wide hops, pack to bf16, MFMA K=64 -> Hcat slice0
    const int n16B = (NN * 4 + 255) / 256;
    prop16_k<<<n16B, 256, 0, stream>>>(x,  P1, rowptr, epair);
    prop16_k<<<n16B, 256, 0, stream>>>(P1, P2, rowptr, epair);
    prop16_k<<<n16B, 256, 0, stream>>>(P2, P3, rowptr, epair);
    pack_k<<<n16B, 256, 0, stream>>>(x, P1, P2, P3, Xcat);
    mgemm2_k<2, 1><<<256, 512, 0, stream>>>(Xcat, Wt0, b0, Hcat, ctr + 0, nTiles);

    // Layer 1: hops fill slices 1..3, fused GEMM K=512 -> slice0 (in place)
    propbf_k<<<nPropB, 256, 0, stream>>>(Hcat,       Hcat + 128, rowptr, epair);
    propbf_k<<<nPropB, 256, 0, stream>>>(Hcat + 128, Hcat + 256, rowptr, epair);
    propbf_k<<<nPropB, 256, 0, stream>>>(Hcat + 256, Hcat + 384, rowptr, epair);
    mgemm2_k<16, 1><<<256, 512, 0, stream>>>(Hcat, Wt1, b1, Hcat, ctr + 1, nTiles);

    // Layer 2: same, final GEMM -> slice0 bf16 (no relu)
    propbf_k<<<nPropB, 256, 0, stream>>>(Hcat,       Hcat + 128, rowptr, epair);
    propbf_k<<<nPropB, 256, 0, stream>>>(Hcat + 128, Hcat + 256, rowptr, epair);
    propbf_k<<<nPropB, 256, 0, stream>>>(Hcat + 256, Hcat + 384, rowptr, epair);
    mgemm2_k<16, 0><<<256, 512, 0, stream>>>(Hcat, Wt2, b2, Hcat, ctr + 2, nTiles);

    // Final projection (reads bf16 slice0)
    fcb_k<<<nPropB, 256, 0, stream>>>(Hcat, Wfc, bfc, out);
}

// Round 7
// 653.896 us; speedup vs baseline: 2.9229x; 1.0415x over previous
//
#include <hip/hip_runtime.h>
#include <cstddef>
#include <cstdint>

// Problem constants (from reference)
#define NN 100000
#define NE 1600000
// F_IN=16, HID=128, OUT=4, K=3

// Coarse bucketing for CSR build: 64 nodes per bucket
#define CB 1563              // ceil(NN/64)
#define CBP 1568             // padded bucket count (multiple of 32)
#define EPB 4096             // edges per block in pass A
#define A1B 391              // ceil(NE/EPB)

typedef unsigned short u16;
using short8 = __attribute__((ext_vector_type(8))) short;  // 8 bf16 (4 VGPRs)
using f32x4  = __attribute__((ext_vector_type(4))) float;  // MFMA accum

// bf16 helpers (round-to-nearest-even via bit trick)
__device__ inline u16 f2bf(float f) {
    unsigned u = __float_as_uint(f);
    unsigned r = u + 0x7fffu + ((u >> 16) & 1u);
    return (u16)(r >> 16);
}
__device__ inline float bflo(unsigned u) { return __uint_as_float(u << 16); }
__device__ inline float bfhi(unsigned u) { return __uint_as_float(u & 0xffff0000u); }

// ---------------------------------------------------------------------------
// Graph preprocessing v2: atomic-free two-level bucket CSR build.
// Pass A partitions edges into 1568 coarse buckets (64 nodes each);
// Pass B counting-sorts each bucket in LDS -> epair + rowptr + dis.
// Only LDS atomics are used (global pattern fully streaming).
// ---------------------------------------------------------------------------

// A1: per-block histogram of coarse buckets -> M[blk][CBP]
__global__ __launch_bounds__(256) void hist_k(const int* __restrict__ col,
                                              unsigned* __restrict__ M) {
    __shared__ unsigned h[CBP];
    for (int i = threadIdx.x; i < CBP; i += 256) h[i] = 0;
    __syncthreads();
    int base = blockIdx.x * EPB;
    for (int i = threadIdx.x; i < EPB; i += 256) {
        int e = base + i;
        if (e < NE) atomicAdd(&h[col[e] >> 6], 1u);
    }
    __syncthreads();
    unsigned* mrow = M + (size_t)blockIdx.x * CBP;
    for (int i = threadIdx.x; i < CBP; i += 256) mrow[i] = h[i];
}

// A2a: column totals of M -> tot[CBP]  (coalesced: thread per bucket)
__global__ __launch_bounds__(256) void totals_k(const unsigned* __restrict__ M,
                                                unsigned* __restrict__ tot) {
    int b = blockIdx.x * 256 + threadIdx.x;
    if (b >= CBP) return;
    unsigned s = 0;
    for (int r = 0; r < A1B; ++r) s += M[(size_t)r * CBP + b];
    tot[b] = s;
}

// A2b: exclusive scan of tot -> cb[0..CBP]  (single block)
__global__ __launch_bounds__(256) void scanb_k(const unsigned* __restrict__ tot,
                                               unsigned* __restrict__ cb) {
    __shared__ unsigned part[256];
    int t = threadIdx.x;
    unsigned loc[7];
    unsigned s = 0;
#pragma unroll
    for (int k = 0; k < 7; ++k) {
        int i = t * 7 + k;
        unsigned v = (i < CBP) ? tot[i] : 0;
        loc[k] = s; s += v;
    }
    part[t] = s;
    __syncthreads();
    for (int off = 1; off < 256; off <<= 1) {
        unsigned x = (t >= off) ? part[t - off] : 0;
        __syncthreads();
        part[t] += x;
        __syncthreads();
    }
    unsigned base = (t > 0) ? part[t - 1] : 0;
#pragma unroll
    for (int k = 0; k < 7; ++k) {
        int i = t * 7 + k;
        if (i <= CBP) cb[i] = base + loc[k];
    }
}

// A2c: rewrite M in place to per-(blk,bucket) base = cb[b] + prefix over blocks
__global__ __launch_bounds__(256) void base_k(const unsigned* __restrict__ cb,
                                              unsigned* __restrict__ M) {
    int b = blockIdx.x * 256 + threadIdx.x;
    if (b >= CBP) return;
    unsigned run = cb[b];
    for (int r = 0; r < A1B; ++r) {
        unsigned v = M[(size_t)r * CBP + b];
        M[(size_t)r * CBP + b] = run;
        run += v;
    }
}

// A3: partition edges into bucket segments (packed: src | colLow<<17, w)
__global__ __launch_bounds__(256) void part_k(const int* __restrict__ row,
                                              const int* __restrict__ col,
                                              const float* __restrict__ ew,
                                              const unsigned* __restrict__ M,
                                              int2* __restrict__ Abuf) {
    __shared__ unsigned cur[CBP];
    const unsigned* mrow = M + (size_t)blockIdx.x * CBP;
    for (int i = threadIdx.x; i < CBP; i += 256) cur[i] = mrow[i];
    __syncthreads();
    int base = blockIdx.x * EPB;
    for (int i = threadIdx.x; i < EPB; i += 256) {
        int e = base + i;
        if (e < NE) {
            int c = col[e];
            unsigned pos = atomicAdd(&cur[c >> 6], 1u);
            Abuf[pos] = make_int2(row[e] | ((c & 63) << 17), __float_as_int(ew[e]));
        }
    }
}

// B: per-bucket LDS counting sort -> epair + rowptr; fused deg/dis.
__global__ __launch_bounds__(256) void build_k(const int2* __restrict__ Abuf,
                                               const unsigned* __restrict__ cb,
                                               int* __restrict__ rowptr,
                                               int2* __restrict__ epair,
                                               float* __restrict__ dis) {
    int b = blockIdx.x;     // 0..CB-1
    int t = threadIdx.x;
    __shared__ int cnt[64];
    __shared__ int offs[64];
    __shared__ int ex[64];
    __shared__ float dsum[64];
    if (t < 64) { cnt[t] = 0; dsum[t] = 0.f; }
    __syncthreads();
    unsigned s = cb[b], e = cb[b + 1];
    int n = (int)(e - s);
    int2 mye[12]; int myb[12]; int myn = 0;
    for (int i = t; i < n; i += 256) {
        int2 p = Abuf[s + i];
        int cl = (p.x >> 17) & 63;
        if (myn < 12) { mye[myn] = p; myb[myn] = cl; ++myn; }
        atomicAdd(&cnt[cl], 1);
        atomicAdd(&dsum[cl], __int_as_float(p.y));
    }
    __syncthreads();
    // exclusive scan of cnt[64]
    if (t < 64) offs[t] = cnt[t];
    __syncthreads();
    for (int off = 1; off < 64; off <<= 1) {
        int x = 0;
        if (t < 64 && t >= off) x = offs[t - off];
        __syncthreads();
        if (t < 64) offs[t] += x;
        __syncthreads();
    }
    if (t < 64) { ex[t] = offs[t] - cnt[t]; cnt[t] = 0; }
    __syncthreads();
    // scatter into sorted positions (LDS cursor ranks)
    for (int k = 0; k < myn; ++k) {
        int cl = myb[k];
        int r = atomicAdd(&cnt[cl], 1);
        epair[s + ex[cl] + r] = make_int2(mye[k].x & 0x1FFFF, mye[k].y);
    }
    // rowptr + dis
    if (t < 64) {
        int v = b * 64 + t;
        if (v < NN) {
            rowptr[v] = (int)s + ex[t];
            float d = dsum[t];
            dis[v] = (d > 0.f) ? (1.0f / sqrtf(d)) : 0.f;
        }
    }
    if (b == CB - 1 && t == 0) rowptr[NN] = NE;
}

// epair[i] = (src, dis[src]*w*dis[v])  -- full 8B store (write-combine friendly)
__global__ void norm_k(const int* __restrict__ rowptr, const float* __restrict__ dis,
                       int2* __restrict__ epair) {
    int v = blockIdx.x * 256 + threadIdx.x;
    if (v >= NN) return;
    float dv = dis[v];
    int s = rowptr[v], e = rowptr[v + 1];
    for (int i = s; i < e; ++i) {
        int2 p = epair[i];
        float w = dis[p.x] * __int_as_float(p.y) * dv;
        epair[i] = make_int2(p.x, __float_as_int(w));
    }
}

// ---------------------------------------------------------------------------
// Weight prep: Wt[j][k] = bf16(W[k][j]);  W is [K][128] fp32, Wt is [128][K]
// ---------------------------------------------------------------------------
template <int K>
__global__ void wt_k(const float* __restrict__ W, u16* __restrict__ Wt) {
    int id = blockIdx.x * 256 + threadIdx.x;   // grid = 128*K/256
    int j = id / K, k = id % K;
    Wt[(size_t)j * K + k] = f2bf(W[(size_t)k * 128 + j]);
}

// ---------------------------------------------------------------------------
// Propagation
// ---------------------------------------------------------------------------

// 16-wide fp32 features (layer-0 hops): 4 lanes per node, float4 each.
__global__ void prop16_k(const float* __restrict__ hin, float* __restrict__ hout,
                         const int* __restrict__ rowptr, const int2* __restrict__ epair) {
    int t = blockIdx.x * 256 + threadIdx.x;
    int v = t >> 2, q = t & 3;
    if (v >= NN) return;
    int s = rowptr[v], e = rowptr[v + 1];
    const float* __restrict__ hq = hin + q * 4;
    float4 a0 = make_float4(0.f, 0.f, 0.f, 0.f);
    float4 a1 = make_float4(0.f, 0.f, 0.f, 0.f);
    int i = s;
    for (; i + 3 < e; i += 4) {
        int2 p0 = epair[i];
        int2 p1 = epair[i + 1];
        int2 p2 = epair[i + 2];
        int2 p3 = epair[i + 3];
        float4 h0 = *reinterpret_cast<const float4*>(hq + (size_t)p0.x * 16);
        float4 h1 = *reinterpret_cast<const float4*>(hq + (size_t)p1.x * 16);
        float4 h2 = *reinterpret_cast<const float4*>(hq + (size_t)p2.x * 16);
        float4 h3 = *reinterpret_cast<const float4*>(hq + (size_t)p3.x * 16);
        float w0 = __int_as_float(p0.y), w1 = __int_as_float(p1.y);
        float w2 = __int_as_float(p2.y), w3 = __int_as_float(p3.y);
        a0.x += w0 * h0.x; a0.y += w0 * h0.y; a0.z += w0 * h0.z; a0.w += w0 * h0.w;
        a1.x += w1 * h1.x; a1.y += w1 * h1.y; a1.z += w1 * h1.z; a1.w += w1 * h1.w;
        a0.x += w2 * h2.x; a0.y += w2 * h2.y; a0.z += w2 * h2.z; a0.w += w2 * h2.w;
        a1.x += w3 * h3.x; a1.y += w3 * h3.y; a1.z += w3 * h3.z; a1.w += w3 * h3.w;
    }
    for (; i < e; ++i) {
        int2 p = epair[i];
        float w = __int_as_float(p.y);
        float4 h = *reinterpret_cast<const float4*>(hq + (size_t)p.x * 16);
        a0.x += w * h.x; a0.y += w * h.y; a0.z += w * h.z; a0.w += w * h.w;
    }
    float4 acc = make_float4(a0.x + a1.x, a0.y + a1.y, a0.z + a1.z, a0.w + a1.w);
    *reinterpret_cast<float4*>(hout + (size_t)v * 16 + q * 4) = acc;
}

// Pack x,P1,P2,P3 (fp32 [NN][16] each) -> Xcat bf16 [NN][64]
__global__ void pack_k(const float* __restrict__ x, const float* __restrict__ p1,
                       const float* __restrict__ p2, const float* __restrict__ p3,
                       u16* __restrict__ Xcat) {
    int id = blockIdx.x * 256 + threadIdx.x;
    if (id >= NN * 4) return;
    int v = id >> 2, s = id & 3;
    const float* src = (s == 0 ? x : s == 1 ? p1 : s == 2 ? p2 : p3) + (size_t)v * 16;
    unsigned* dst = (unsigned*)(Xcat + (size_t)v * 64 + s * 16);
#pragma unroll
    for (int f = 0; f < 8; ++f) {
        dst[f] = (unsigned)f2bf(src[2 * f]) | ((unsigned)f2bf(src[2 * f + 1]) << 16);
    }
}

// 128-wide bf16 prop: ONE wave per node; 16 lanes serve one edge with
// dwordx4 (16B = 8 features per lane) -> 4 edges per wave-load, unroll x2.
__global__ __launch_bounds__(256) void propbf_k(
    const u16* __restrict__ hin, u16* __restrict__ hout,
    const int* __restrict__ rowptr, const int2* __restrict__ epair) {
    int wid = (blockIdx.x * 256 + threadIdx.x) >> 6;   // grid = NN*64/256
    int lane = threadIdx.x & 63;
    int g = lane >> 4;          // edge group 0..3
    int l = lane & 15;          // feature slot: features [8l, 8l+8)
    int v = __builtin_amdgcn_readfirstlane(wid);
    int s = rowptr[v], e = rowptr[v + 1];
    const u16* __restrict__ hb = hin + l * 8;
    float a[8];
#pragma unroll
    for (int k = 0; k < 8; ++k) a[k] = 0.f;

    int i = s;
    for (; i + 7 < e; i += 8) {
        int2 pa = epair[i + g];
        int2 pb = epair[i + 4 + g];
        uint4 ha = *(const uint4*)(hb + (size_t)pa.x * 512);
        uint4 hc = *(const uint4*)(hb + (size_t)pb.x * 512);
        float wa = __int_as_float(pa.y), wb = __int_as_float(pb.y);
        a[0] += wa * bflo(ha.x); a[1] += wa * bfhi(ha.x);
        a[2] += wa * bflo(ha.y); a[3] += wa * bfhi(ha.y);
        a[4] += wa * bflo(ha.z); a[5] += wa * bfhi(ha.z);
        a[6] += wa * bflo(ha.w); a[7] += wa * bfhi(ha.w);
        a[0] += wb * bflo(hc.x); a[1] += wb * bfhi(hc.x);
        a[2] += wb * bflo(hc.y); a[3] += wb * bfhi(hc.y);
        a[4] += wb * bflo(hc.z); a[5] += wb * bfhi(hc.z);
        a[6] += wb * bflo(hc.w); a[7] += wb * bfhi(hc.w);
    }
    for (; i < e; i += 4) {
        int idx = i + g;
        int2 p = (idx < e) ? epair[idx] : make_int2(0, 0);
        uint4 h = *(const uint4*)(hb + (size_t)p.x * 512);
        float w = __int_as_float(p.y);
        a[0] += w * bflo(h.x); a[1] += w * bfhi(h.x);
        a[2] += w * bflo(h.y); a[3] += w * bfhi(h.y);
        a[4] += w * bflo(h.z); a[5] += w * bfhi(h.z);
        a[6] += w * bflo(h.w); a[7] += w * bfhi(h.w);
    }
#pragma unroll
    for (int k = 0; k < 8; ++k) {
        a[k] += __shfl_xor(a[k], 16);
        a[k] += __shfl_xor(a[k], 32);
    }
    if (g == 0) {
        uint4 o;
        o.x = (unsigned)f2bf(a[0]) | ((unsigned)f2bf(a[1]) << 16);
        o.y = (unsigned)f2bf(a[2]) | ((unsigned)f2bf(a[3]) << 16);
        o.z = (unsigned)f2bf(a[4]) | ((unsigned)f2bf(a[5]) << 16);
        o.w = (unsigned)f2bf(a[6]) | ((unsigned)f2bf(a[7]) << 16);
        *(uint4*)(hout + (size_t)v * 512 + l * 8) = o;
    }
}

// ---------------------------------------------------------------------------
// MFMA GEMM: C[NN][128] = A[NN][K]bf16 @ W[K][128] (+bias, relu) -> bf16
// out stride 512. LDS-staged swizzled Bt, persistent 8-wave blocks + ticket.
// ---------------------------------------------------------------------------
template <int KSTEPS, int RELU>
__global__ __launch_bounds__(512, 2) void mgemm2_k(
    const u16* __restrict__ A, const u16* __restrict__ Bt,
    const float* __restrict__ bias, u16* __restrict__ outb,
    int* __restrict__ ctr, int ntiles) {
    const int K = KSTEPS * 32;
    const int BBYTES = 128 * K * 2;
    __shared__ u16 smB[128 * KSTEPS * 32];
    __shared__ int smt;
    int tid = threadIdx.x;

    for (int d = tid * 16; d < BBYTES; d += 512 * 16) {
        int rowb = d / (K * 2);
        int src = d ^ ((rowb & 7) << 4);
        *(short8*)((char*)smB + d) = *(const short8*)((const char*)Bt + src);
    }

    int lane = tid & 63;
    int wv = tid >> 6;
    int r = lane & 15, h = lane >> 4;
    float bj[8];
#pragma unroll
    for (int j = 0; j < 8; ++j) bj[j] = bias[j * 16 + r];
    const char* bbase = (const char*)smB;

    for (;;) {
        __syncthreads();
        if (tid == 0) smt = atomicAdd(ctr, 1);
        __syncthreads();
        int t = smt;
        if (t >= ntiles) break;
        int v0 = t * 256 + wv * 32;
        if (v0 >= NN) continue;

        const u16* a0p = A + (size_t)(v0 + r) * K + h * 8;
        const u16* a1p = a0p + (size_t)16 * K;
        f32x4 acc0[8], acc1[8];
#pragma unroll
        for (int j = 0; j < 8; ++j) {
            acc0[j] = {0.f, 0.f, 0.f, 0.f};
            acc1[j] = {0.f, 0.f, 0.f, 0.f};
        }
#pragma unroll
        for (int kk = 0; kk < KSTEPS; ++kk) {
            short8 a0 = *(const short8*)(a0p + kk * 32);
            short8 a1 = *(const short8*)(a1p + kk * 32);
#pragma unroll
            for (int j = 0; j < 8; ++j) {
                int bb = ((j * 16 + r) * K * 2 + kk * 64 + h * 16) ^ ((r & 7) << 4);
                short8 b = *(const short8*)(bbase + bb);
                acc0[j] = __builtin_amdgcn_mfma_f32_16x16x32_bf16(a0, b, acc0[j], 0, 0, 0);
                acc1[j] = __builtin_amdgcn_mfma_f32_16x16x32_bf16(a1, b, acc1[j], 0, 0, 0);
            }
        }
#pragma unroll
        for (int i = 0; i < 4; ++i) {
            int row0 = v0 + h * 4 + i;
#pragma unroll
            for (int j = 0; j < 8; ++j) {
                float c0 = acc0[j][i] + bj[j];
                float c1 = acc1[j][i] + bj[j];
                if (RELU) { c0 = fmaxf(c0, 0.f); c1 = fmaxf(c1, 0.f); }
                outb[(size_t)row0 * 512 + j * 16 + r] = f2bf(c0);
                outb[(size_t)(row0 + 16) * 512 + j * 16 + r] = f2bf(c1);
            }
        }
    }
}

// Final fc: out[v][0..3] = bfc + h[v][:] @ Wfc[128][4]; h bf16 stride 512.
__global__ void fcb_k(const u16* __restrict__ H, const float* __restrict__ Wfc,
                      const float* __restrict__ bfc, float* __restrict__ out) {
    int t = blockIdx.x * 256 + threadIdx.x;   // grid = NN*64/256
    int v = t >> 6, p = t & 63;
    unsigned u = *(const unsigned*)(H + (size_t)v * 512 + p * 2);
    float h0 = bflo(u), h1 = bfhi(u);
    float4 w0 = reinterpret_cast<const float4*>(Wfc)[2 * p];
    float4 w1 = reinterpret_cast<const float4*>(Wfc)[2 * p + 1];
    float s0 = h0 * w0.x + h1 * w1.x;
    float s1 = h0 * w0.y + h1 * w1.y;
    float s2 = h0 * w0.z + h1 * w1.z;
    float s3 = h0 * w0.w + h1 * w1.w;
#pragma unroll
    for (int off = 32; off; off >>= 1) {
        s0 += __shfl_xor(s0, off);
        s1 += __shfl_xor(s1, off);
        s2 += __shfl_xor(s2, off);
        s3 += __shfl_xor(s3, off);
    }
    if (p == 0) {
        float4 o = make_float4(s0 + bfc[0], s1 + bfc[1], s2 + bfc[2], s3 + bfc[3]);
        reinterpret_cast<float4*>(out)[v] = o;
    }
}

// ---------------------------------------------------------------------------

extern "C" void kernel_launch(void* const* d_in, const int* in_sizes, int n_in,
                              void* d_out, int out_size, void* d_ws, size_t ws_size,
                              hipStream_t stream) {
    const float* x    = (const float*)d_in[0];
    const int*   ei   = (const int*)d_in[1];      // [2][E] int32
    const float* ea   = (const float*)d_in[2];    // [E]
    const float* W0   = (const float*)d_in[3];    // [4][16][128] = [64][128]
    const float* b0   = (const float*)d_in[4];
    const float* W1   = (const float*)d_in[5];    // [4][128][128] = [512][128]
    const float* b1   = (const float*)d_in[6];
    const float* W2   = (const float*)d_in[7];
    const float* b2   = (const float*)d_in[8];
    const float* Wfc  = (const float*)d_in[9];    // [128][4]
    const float* bfc  = (const float*)d_in[10];
    float* out = (float*)d_out;

    const int* row = ei;
    const int* col = ei + NE;

    // ws layout (256B aligned chunks), ~183 MB total
    char* w = (char*)d_ws;
    size_t off = 0;
    auto alloc = [&](size_t bytes) {
        size_t o = off;
        off += (bytes + 255) & ~(size_t)255;
        return (void*)(w + o);
    };
    int*      ctr    = (int*)     alloc(3 * 4);          // first (memset)
    size_t zero_bytes = off;
    int*      rowptr = (int*)     alloc((size_t)(NN + 1) * 4);
    float*    dis    = (float*)   alloc((size_t)NN * 4);
    unsigned* M      = (unsigned*)alloc((size_t)A1B * CBP * 4);  // 2.45 MB
    unsigned* tot    = (unsigned*)alloc((size_t)CBP * 4);
    unsigned* cb     = (unsigned*)alloc((size_t)(CBP + 1) * 4);
    int2*     Abuf   = (int2*)    alloc((size_t)NE * 8);         // 12.8 MB
    int2*     epair  = (int2*)    alloc((size_t)NE * 8);         // 12.8 MB
    u16*      Wt0    = (u16*)     alloc((size_t)128 * 64 * 2);
    u16*      Wt1    = (u16*)     alloc((size_t)128 * 512 * 2);
    u16*      Wt2    = (u16*)     alloc((size_t)128 * 512 * 2);
    char*     ureg   = (char*)    alloc((size_t)NN * 128 * 4);   // 51.2 MB
    float* P1   = (float*)(ureg);
    float* P2   = (float*)(ureg + (size_t)NN * 16 * 4);
    float* P3   = (float*)(ureg + (size_t)NN * 32 * 4);
    u16*   Xcat = (u16*)  (ureg + (size_t)NN * 48 * 4);
    u16*      Hcat   = (u16*)     alloc((size_t)NN * 512 * 2);   // 102.4 MB
    (void)ws_size;

    const int nScanB = (NN + 255) / 256;  // 391
    const int nPropB = NN * 64 / 256;     // 25000 (one wave per node)
    const int nTiles = (NN + 255) / 256;  // 391 row-tiles of 256
    const int nBkt   = (CBP + 255) / 256; // 7

    hipMemsetAsync(ctr, 0, zero_bytes, stream);

    // CSR build (atomic-free, streaming)
    hist_k  <<<A1B,  256, 0, stream>>>(col, M);
    totals_k<<<nBkt, 256, 0, stream>>>(M, tot);
    scanb_k <<<1,    256, 0, stream>>>(tot, cb);
    base_k  <<<nBkt, 256, 0, stream>>>(cb, M);
    part_k  <<<A1B,  256, 0, stream>>>(row, col, ea, M, Abuf);
    build_k <<<CB,   256, 0, stream>>>(Abuf, cb, rowptr, epair, dis);
    norm_k  <<<nScanB, 256, 0, stream>>>(rowptr, dis, epair);

    // Weight transposes (bf16)
    wt_k<64> <<<32,  256, 0, stream>>>(W0, Wt0);
    wt_k<512><<<256, 256, 0, stream>>>(W1, Wt1);
    wt_k<512><<<256, 256, 0, stream>>>(W2, Wt2);

    // Layer 0: fp32 16-wide hops, pack to bf16, MFMA K=64 -> Hcat slice0
    const int n16B = (NN * 4 + 255) / 256;
    prop16_k<<<n16B, 256, 0, stream>>>(x,  P1, rowptr, epair);
    prop16_k<<<n16B, 256, 0, stream>>>(P1, P2, rowptr, epair);
    prop16_k<<<n16B, 256, 0, stream>>>(P2, P3, rowptr, epair);
    pack_k<<<n16B, 256, 0, stream>>>(x, P1, P2, P3, Xcat);
    mgemm2_k<2, 1><<<256, 512, 0, stream>>>(Xcat, Wt0, b0, Hcat, ctr + 0, nTiles);

    // Layer 1: hops fill slices 1..3, fused GEMM K=512 -> slice0 (in place)
    propbf_k<<<nPropB, 256, 0, stream>>>(Hcat,       Hcat + 128, rowptr, epair);
    propbf_k<<<nPropB, 256, 0, stream>>>(Hcat + 128, Hcat + 256, rowptr, epair);
    propbf_k<<<nPropB, 256, 0, stream>>>(Hcat + 256, Hcat + 384, rowptr, epair);
    mgemm2_k<16, 1><<<256, 512, 0, stream>>>(Hcat, Wt1, b1, Hcat, ctr + 1, nTiles);

    // Layer 2: same, final GEMM -> slice0 bf16 (no relu)
    propbf_k<<<nPropB, 256, 0, stream>>>(Hcat,       Hcat + 128, rowptr, epair);
    propbf_k<<<nPropB, 256, 0, stream>>>(Hcat + 128, Hcat + 256, rowptr, epair);
    propbf_k<<<nPropB, 256, 0, stream>>>(Hcat + 256, Hcat + 384, rowptr, epair);
    mgemm2_k<16, 0><<<256, 512, 0, stream>>>(Hcat, Wt2, b2, Hcat, ctr + 2, nTiles);

    // Final projection (reads bf16 slice0)
    fcb_k<<<nPropB, 256, 0, stream>>>(Hcat, Wfc, bfc, out);
}